// Round 1
// baseline (5751.356 us; speedup 1.0000x reference)
//
#include <hip/hip_runtime.h>

constexpr int N  = 50000;
constexpr int M  = 800000;
constexpr int D  = 128;
constexpr int IN = 192;   // D + EF + DF
constexpr int TE = 32;    // edges per block
constexpr int TN = 32;    // nodes per block (LSTM)

__device__ __forceinline__ float sigm(float x) { return 1.0f / (1.0f + __expf(-x)); }

// ---------------- init: state = node_feat (in d_out), state_c = node_feat_c ----------------
__global__ void init_kernel(const float4* __restrict__ nf, const float4* __restrict__ nfc,
                            float4* __restrict__ state, float4* __restrict__ state_c) {
    const int total = N * D / 4;
    for (int i = blockIdx.x * blockDim.x + threadIdx.x; i < total; i += gridDim.x * blockDim.x) {
        state[i]   = nf[i];
        state_c[i] = nfc[i];
    }
}

// ---------------- relu(state) in place (ii>0) + zero state_msg ----------------
__global__ void relu_zero_kernel(float4* __restrict__ state, float4* __restrict__ msg, int do_relu) {
    const int total = N * D / 4;
    const float4 z = make_float4(0.f, 0.f, 0.f, 0.f);
    for (int i = blockIdx.x * blockDim.x + threadIdx.x; i < total; i += gridDim.x * blockDim.x) {
        if (do_relu) {
            float4 v = state[i];
            v.x = fmaxf(v.x, 0.f); v.y = fmaxf(v.y, 0.f);
            v.z = fmaxf(v.z, 0.f); v.w = fmaxf(v.w, 0.f);
            state[i] = v;
        }
        msg[i] = z;
    }
}

// ---------------- fused edge kernel ----------------
struct EdgeSmem {
    float4 in4[TE][IN / 4];  // 32 x 48 = 24.0 KB  edge_input
    float4 h4[TE][D / 4];    // 32 x 32 = 16.0 KB  hidden
    float4 w4[32][D / 4];    // 32 x 32 = 16.0 KB  weight tile (32 k-rows x 128 cols)
    int    ed[TE][2];
};

// C[32 x 128] = A[32 x K] @ W[K x 128]; thread tile: 4 edges x 4 cols.
__device__ __forceinline__ void gemm_block(EdgeSmem& sm, const float* __restrict__ sA,
                                           const int lda, const int K,
                                           const float4* __restrict__ W4,
                                           const int t, const int tc, const int eb,
                                           float acc[4][4]) {
#pragma unroll
    for (int j = 0; j < 4; ++j)
#pragma unroll
        for (int q = 0; q < 4; ++q) acc[j][q] = 0.f;

    for (int kt = 0; kt < K; kt += 32) {
        // stage 32 x 128 weight tile (coalesced float4)
#pragma unroll
        for (int i = 0; i < 4; ++i) {
            const int idx = t + i * 256;                 // 0..1023
            sm.w4[idx >> 5][idx & 31] = W4[(kt + (idx >> 5)) * 32 + (idx & 31)];
        }
        __syncthreads();
#pragma unroll 2
        for (int kk = 0; kk < 32; kk += 4) {
            float4 a[4], w[4];
#pragma unroll
            for (int j = 0; j < 4; ++j)
                a[j] = *(const float4*)&sA[(eb + j) * lda + kt + kk];
#pragma unroll
            for (int kz = 0; kz < 4; ++kz) w[kz] = sm.w4[kk + kz][tc];
#pragma unroll
            for (int j = 0; j < 4; ++j) {
#define FMA4(av, wv) \
                acc[j][0] = fmaf(av, wv.x, acc[j][0]); \
                acc[j][1] = fmaf(av, wv.y, acc[j][1]); \
                acc[j][2] = fmaf(av, wv.z, acc[j][2]); \
                acc[j][3] = fmaf(av, wv.w, acc[j][3]);
                FMA4(a[j].x, w[0])
                FMA4(a[j].y, w[1])
                FMA4(a[j].z, w[2])
                FMA4(a[j].w, w[3])
#undef FMA4
            }
        }
        __syncthreads();
    }
}

__global__ __launch_bounds__(256)
void edge_kernel(const float* __restrict__ state, const int* __restrict__ edge,
                 const float4* __restrict__ ef4, const float4* __restrict__ df4,
                 const float* __restrict__ w0m, const float* __restrict__ b0m,
                 const float* __restrict__ w1m, const float* __restrict__ b1m,
                 const float* __restrict__ w0a, const float* __restrict__ b0a,
                 const float* __restrict__ w1a, const float* __restrict__ b1a,
                 float* __restrict__ state_msg) {
    __shared__ EdgeSmem sm;
    const int t  = threadIdx.x;
    const int e0 = blockIdx.x * TE;

    if (t < TE * 2) sm.ed[t >> 1][t & 1] = edge[e0 * 2 + t];
    __syncthreads();

    // gather edge_input = [state[src]-state[dst] | edge_feat | dist_feat]
    const float4* st4 = (const float4*)state;
#pragma unroll
    for (int i = 0; i < 6; ++i) {
        const int idx = t + i * 256;                    // 0..1535
        const int e = idx / 48, c = idx - e * 48;
        float4 v;
        if (c < 32) {
            const float4 a = st4[(size_t)sm.ed[e][0] * 32 + c];
            const float4 b = st4[(size_t)sm.ed[e][1] * 32 + c];
            v = make_float4(a.x - b.x, a.y - b.y, a.z - b.z, a.w - b.w);
        } else if (c < 40) {
            v = ef4[(size_t)(e0 + e) * 8 + (c - 32)];
        } else {
            v = df4[(size_t)(e0 + e) * 8 + (c - 40)];
        }
        sm.in4[e][c] = v;
    }
    // (no explicit sync needed: gemm_block's staging barrier orders these writes before reads)

    const int tc = t & 31;          // col group: cols tc*4 .. tc*4+3
    const int eb = (t >> 5) * 4;    // edge group: edges eb .. eb+3
    float acc[4][4], msgv[4][4];
    float* sh        = (float*)sm.h4;
    const float* sin = (const float*)sm.in4;

    // ---- msg path ----
    gemm_block(sm, sin, IN, IN, (const float4*)w0m, t, tc, eb, acc);
#pragma unroll
    for (int j = 0; j < 4; ++j)
#pragma unroll
        for (int q = 0; q < 4; ++q)
            sh[(eb + j) * D + tc * 4 + q] = fmaxf(acc[j][q] + b0m[tc * 4 + q], 0.f);
    gemm_block(sm, sh, D, D, (const float4*)w1m, t, tc, eb, msgv);
#pragma unroll
    for (int j = 0; j < 4; ++j)
#pragma unroll
        for (int q = 0; q < 4; ++q) msgv[j][q] += b1m[tc * 4 + q];

    // ---- att path ----
    gemm_block(sm, sin, IN, IN, (const float4*)w0a, t, tc, eb, acc);
#pragma unroll
    for (int j = 0; j < 4; ++j)
#pragma unroll
        for (int q = 0; q < 4; ++q)
            sh[(eb + j) * D + tc * 4 + q] = fmaxf(acc[j][q] + b0a[tc * 4 + q], 0.f);
    gemm_block(sm, sh, D, D, (const float4*)w1a, t, tc, eb, acc);

    // ---- combine + scatter ----
#pragma unroll
    for (int j = 0; j < 4; ++j) {
        float* row = state_msg + (size_t)sm.ed[eb + j][1] * D + tc * 4;
#pragma unroll
        for (int q = 0; q < 4; ++q)
            atomicAdd(row + q, msgv[j][q] * sigm(acc[j][q] + b1a[tc * 4 + q]));
    }
}

// ---------------- LSTM cell over nodes ----------------
__global__ __launch_bounds__(256)
void lstm_kernel(const float4* __restrict__ x4g, float* __restrict__ hbuf,
                 float* __restrict__ cbuf,
                 const float* __restrict__ wih, const float* __restrict__ whh,
                 const float* __restrict__ bih, const float* __restrict__ bhh) {
    __shared__ float4 s_x[TN][D / 4];
    __shared__ float4 s_h[TN][D / 4];
    const int t  = threadIdx.x;
    const int n0 = blockIdx.x * TN;
    const float4* h4g = (const float4*)hbuf;

#pragma unroll
    for (int i = 0; i < 4; ++i) {
        const int idx = t + i * 256;                   // 0..1023
        const int n = idx >> 5, cc = idx & 31;
        float4 vx = make_float4(0.f, 0.f, 0.f, 0.f), vh = vx;
        if (n0 + n < N) {
            vx = x4g[(size_t)(n0 + n) * 32 + cc];
            vh = h4g[(size_t)(n0 + n) * 32 + cc];
        }
        s_x[n][cc] = vx;
        s_h[n][cc] = vh;
    }
    __syncthreads();

    const int tc = t & 63;          // columns tc*2, tc*2+1 of each i/f/g/o quadrant
    const int nb = (t >> 6) * 8;    // 8 nodes per thread

    float acc[4][2][8];
#pragma unroll
    for (int q = 0; q < 4; ++q)
#pragma unroll
        for (int cc = 0; cc < 2; ++cc)
#pragma unroll
            for (int nn = 0; nn < 8; ++nn) acc[q][cc][nn] = 0.f;

#pragma unroll 1
    for (int k4 = 0; k4 < 32; ++k4) {
        float4 v[8];
#pragma unroll
        for (int nn = 0; nn < 8; ++nn) v[nn] = s_x[nb + nn][k4];
#pragma unroll
        for (int q = 0; q < 4; ++q)
#pragma unroll
            for (int cc = 0; cc < 2; ++cc) {
                const float4 w = *(const float4*)&wih[(size_t)(q * 128 + tc * 2 + cc) * D + k4 * 4];
#pragma unroll
                for (int nn = 0; nn < 8; ++nn) {
                    acc[q][cc][nn] = fmaf(v[nn].x, w.x, acc[q][cc][nn]);
                    acc[q][cc][nn] = fmaf(v[nn].y, w.y, acc[q][cc][nn]);
                    acc[q][cc][nn] = fmaf(v[nn].z, w.z, acc[q][cc][nn]);
                    acc[q][cc][nn] = fmaf(v[nn].w, w.w, acc[q][cc][nn]);
                }
            }
#pragma unroll
        for (int nn = 0; nn < 8; ++nn) v[nn] = s_h[nb + nn][k4];
#pragma unroll
        for (int q = 0; q < 4; ++q)
#pragma unroll
            for (int cc = 0; cc < 2; ++cc) {
                const float4 w = *(const float4*)&whh[(size_t)(q * 128 + tc * 2 + cc) * D + k4 * 4];
#pragma unroll
                for (int nn = 0; nn < 8; ++nn) {
                    acc[q][cc][nn] = fmaf(v[nn].x, w.x, acc[q][cc][nn]);
                    acc[q][cc][nn] = fmaf(v[nn].y, w.y, acc[q][cc][nn]);
                    acc[q][cc][nn] = fmaf(v[nn].z, w.z, acc[q][cc][nn]);
                    acc[q][cc][nn] = fmaf(v[nn].w, w.w, acc[q][cc][nn]);
                }
            }
    }

#pragma unroll
    for (int cc = 0; cc < 2; ++cc) {
        const int col = tc * 2 + cc;
        const float bi = bih[col]       + bhh[col];
        const float bf = bih[128 + col] + bhh[128 + col];
        const float bg = bih[256 + col] + bhh[256 + col];
        const float bo = bih[384 + col] + bhh[384 + col];
#pragma unroll
        for (int nn = 0; nn < 8; ++nn) {
            const int n = n0 + nb + nn;
            if (n < N) {
                const float gi = acc[0][cc][nn] + bi;
                const float gf = acc[1][cc][nn] + bf;
                const float gg = acc[2][cc][nn] + bg;
                const float go = acc[3][cc][nn] + bo;
                float* cp = cbuf + (size_t)n * D + col;
                const float c2 = sigm(gf) * (*cp) + sigm(gi) * tanhf(gg);
                const float h2 = sigm(go) * tanhf(c2);
                *cp = c2;
                hbuf[(size_t)n * D + col] = h2;
            }
        }
    }
}

extern "C" void kernel_launch(void* const* d_in, const int* in_sizes, int n_in,
                              void* d_out, int out_size, void* d_ws, size_t ws_size,
                              hipStream_t stream) {
    const float* node_feat   = (const float*)d_in[0];
    const float* node_feat_c = (const float*)d_in[1];
    const int*   edge        = (const int*)d_in[2];
    const float* edge_feat   = (const float*)d_in[3];
    const float* dist_feat   = (const float*)d_in[4];
    const float* msg_w0 = (const float*)d_in[5];
    const float* msg_b0 = (const float*)d_in[6];
    const float* msg_w1 = (const float*)d_in[7];
    const float* msg_b1 = (const float*)d_in[8];
    const float* att_w0 = (const float*)d_in[9];
    const float* att_b0 = (const float*)d_in[10];
    const float* att_w1 = (const float*)d_in[11];
    const float* att_b1 = (const float*)d_in[12];
    const float* lstm_wih = (const float*)d_in[13];
    const float* lstm_whh = (const float*)d_in[14];
    const float* lstm_bih = (const float*)d_in[15];
    const float* lstm_bhh = (const float*)d_in[16];

    float* state     = (float*)d_out;                       // h lives in d_out
    float* state_c   = (float*)d_ws;                        // N*D f32
    float* state_msg = (float*)d_ws + (size_t)N * D;        // N*D f32

    init_kernel<<<2048, 256, 0, stream>>>((const float4*)node_feat, (const float4*)node_feat_c,
                                          (float4*)state, (float4*)state_c);

    for (int ii = 0; ii < 2; ++ii) {
        relu_zero_kernel<<<2048, 256, 0, stream>>>((float4*)state, (float4*)state_msg, ii > 0 ? 1 : 0);

        edge_kernel<<<M / TE, 256, 0, stream>>>(
            state, edge, (const float4*)edge_feat, (const float4*)dist_feat,
            msg_w0 + (size_t)ii * IN * D, msg_b0 + (size_t)ii * D,
            msg_w1 + (size_t)ii * D * D,  msg_b1 + (size_t)ii * D,
            att_w0 + (size_t)ii * IN * D, att_b0 + (size_t)ii * D,
            att_w1 + (size_t)ii * D * D,  att_b1 + (size_t)ii * D,
            state_msg);

        lstm_kernel<<<(N + TN - 1) / TN, 256, 0, stream>>>(
            (const float4*)state_msg, state, state_c,
            lstm_wih + (size_t)ii * 4 * D * D, lstm_whh + (size_t)ii * 4 * D * D,
            lstm_bih + (size_t)ii * 4 * D,     lstm_bhh + (size_t)ii * 4 * D);
    }
}

// Round 2
// 2399.651 us; speedup vs baseline: 2.3967x; 2.3967x over previous
//
#include <hip/hip_runtime.h>

constexpr int N  = 50000;
constexpr int M  = 800000;
constexpr int D  = 128;
constexpr int IN = 192;   // D + EF + DF
constexpr int TE = 64;    // edges per block (edge kernel)
constexpr int TN = 32;    // nodes per block (LSTM)

typedef __attribute__((ext_vector_type(8)))  short short8;
typedef __attribute__((ext_vector_type(16))) float f32x16;

// packed bf16 weights: 2 layers x { msg:[W0 24576 | W1 16384] , att:[same] } = 163840 shorts
__device__ __align__(16) short g_wp[163840];

__device__ __forceinline__ float sigm(float x) { return 1.0f / (1.0f + __expf(-x)); }

__device__ __forceinline__ short f2bf(float f) {
    unsigned u = __builtin_bit_cast(unsigned, f);
    u = (u + 0x7FFFu + ((u >> 16) & 1u)) >> 16;   // RNE
    return (short)u;
}

// ---------------- weight pack: fp32 -> bf16 MFMA B-fragment order ----------------
// frag f=(kt*4+ct)*64+lane, elem e: B[k=kt*16+(lane>>5)*8+e][col=ct*32+(lane&31)]
__global__ void pack_kernel(const float* __restrict__ w0m, const float* __restrict__ w0a,
                            const float* __restrict__ w1m, const float* __restrict__ w1a) {
    int gid = blockIdx.x * 256 + threadIdx.x;          // 0..163839
    int ii = gid / 81920;
    int r  = gid % 81920;
    int p  = r / 40960;  r %= 40960;
    int which = (r >= 24576) ? 1 : 0;
    int r2 = which ? r - 24576 : r;
    int e    = r2 & 7;
    int f    = r2 >> 3;
    int lane = f & 63;
    int ktct = f >> 6;
    int ct = ktct & 3, kt = ktct >> 2;
    int k   = kt * 16 + ((lane >> 5) << 3) + e;
    int col = ct * 32 + (lane & 31);
    const float* w0 = p ? w0a : w0m;
    const float* w1 = p ? w1a : w1m;
    float v = which ? w1[((size_t)ii * D + k) * D + col]
                    : w0[((size_t)ii * IN + k) * D + col];
    g_wp[gid] = f2bf(v);
}

// ---------------- init / relu+zero ----------------
__global__ void init_kernel(const float4* __restrict__ nf, const float4* __restrict__ nfc,
                            float4* __restrict__ state, float4* __restrict__ state_c) {
    const int total = N * D / 4;
    for (int i = blockIdx.x * blockDim.x + threadIdx.x; i < total; i += gridDim.x * blockDim.x) {
        state[i]   = nf[i];
        state_c[i] = nfc[i];
    }
}

__global__ void relu_zero_kernel(float4* __restrict__ state, float4* __restrict__ msg, int do_relu) {
    const int total = N * D / 4;
    const float4 z = make_float4(0.f, 0.f, 0.f, 0.f);
    for (int i = blockIdx.x * blockDim.x + threadIdx.x; i < total; i += gridDim.x * blockDim.x) {
        if (do_relu) {
            float4 v = state[i];
            v.x = fmaxf(v.x, 0.f); v.y = fmaxf(v.y, 0.f);
            v.z = fmaxf(v.z, 0.f); v.w = fmaxf(v.w, 0.f);
            state[i] = v;
        }
        msg[i] = z;
    }
}

// ---------------- MFMA edge kernel ----------------
// one path: stage W0 -> GEMM1 -> h=relu(.+b0) to LDS -> stage W1 -> GEMM2 -> c0,c1
__device__ __forceinline__ void run_path(const short* __restrict__ gwp, const float* __restrict__ b0,
                                         short* wp, short (*hs)[32][136], const short8 a1[12],
                                         int tid, int lane, int rt, int cg,
                                         f32x16& c0, f32x16& c1) {
    // stage W0: 24576 shorts = 3072 short8
    {
        const short8* src = (const short8*)gwp;
        short8* dst = (short8*)wp;
        for (int i = tid; i < 3072; i += 256) dst[i] = src[i];
    }
    __syncthreads();

    f32x16 acc0 = {}, acc1 = {};
    const short8* wpv = (const short8*)wp;
#pragma unroll
    for (int kt = 0; kt < 12; ++kt) {
        short8 bf0 = wpv[(kt * 4 + cg * 2 + 0) * 64 + lane];
        short8 bf1 = wpv[(kt * 4 + cg * 2 + 1) * 64 + lane];
        acc0 = __builtin_amdgcn_mfma_f32_32x32x16_bf16(a1[kt], bf0, acc0, 0, 0, 0);
        acc1 = __builtin_amdgcn_mfma_f32_32x32x16_bf16(a1[kt], bf1, acc1, 0, 0, 0);
    }
    __syncthreads();   // all waves' GEMM1 LDS reads done -> wp reusable

    // h = relu(acc + b0)  (bf16 into padded LDS)
#pragma unroll
    for (int ct = 0; ct < 2; ++ct) {
        const int col = cg * 64 + ct * 32 + (lane & 31);
        const float bv = b0[col];
        f32x16 a = ct ? acc1 : acc0;
#pragma unroll
        for (int reg = 0; reg < 16; ++reg) {
            const int row = (reg & 3) + 8 * (reg >> 2) + 4 * (lane >> 5);
            hs[rt][row][col] = f2bf(fmaxf(a[reg] + bv, 0.f));
        }
    }

    // stage W1: 16384 shorts = 2048 short8
    {
        const short8* src = (const short8*)(gwp + 24576);
        short8* dst = (short8*)wp;
        for (int i = tid; i < 2048; i += 256) dst[i] = src[i];
    }
    __syncthreads();   // W1 staged AND h visible

    c0 = (f32x16){}; c1 = (f32x16){};
    const int half = (lane >> 5) << 3;
#pragma unroll
    for (int kt = 0; kt < 8; ++kt) {
        short8 a2  = *(const short8*)&hs[rt][lane & 31][kt * 16 + half];
        short8 bf0 = wpv[(kt * 4 + cg * 2 + 0) * 64 + lane];
        short8 bf1 = wpv[(kt * 4 + cg * 2 + 1) * 64 + lane];
        c0 = __builtin_amdgcn_mfma_f32_32x32x16_bf16(a2, bf0, c0, 0, 0, 0);
        c1 = __builtin_amdgcn_mfma_f32_32x32x16_bf16(a2, bf1, c1, 0, 0, 0);
    }
    __syncthreads();   // GEMM2 reads done -> wp & hs reusable by next path
}

__global__ __launch_bounds__(256, 2)
void edge_mfma(const float* __restrict__ state, const int* __restrict__ edge,
               const float* __restrict__ ef, const float* __restrict__ df,
               int ii,
               const float* __restrict__ b0m, const float* __restrict__ b1m,
               const float* __restrict__ b0a, const float* __restrict__ b1a,
               float* __restrict__ state_msg) {
    __shared__ short wp[24576];          // 48 KB weight stage (W0, reused for W1)
    __shared__ short hs[2][32][136];     // 17 KB hidden, padded stride
    __shared__ int   sdst[TE];

    const int tid  = threadIdx.x;
    const int lane = tid & 63;
    const int w    = tid >> 6;
    const int rt   = w >> 1, cg = w & 1;
    const int e0   = blockIdx.x * TE;

    if (tid < TE) sdst[tid] = edge[(e0 + tid) * 2 + 1];

    // ---- gather A1 fragments straight into registers
    const int er   = e0 + rt * 32 + (lane & 31);
    const int half = (lane >> 5) << 3;
    const int s  = edge[er * 2];
    const int d2 = edge[er * 2 + 1];
    const float* srow = state + (size_t)s  * D;
    const float* drow = state + (size_t)d2 * D;
    short8 a1[12];
#pragma unroll
    for (int kt = 0; kt < 8; ++kt) {
        const int k0 = kt * 16 + half;
        float4 u0 = *(const float4*)(srow + k0);
        float4 u1 = *(const float4*)(srow + k0 + 4);
        float4 v0 = *(const float4*)(drow + k0);
        float4 v1 = *(const float4*)(drow + k0 + 4);
        short8 t;
        t[0] = f2bf(u0.x - v0.x); t[1] = f2bf(u0.y - v0.y);
        t[2] = f2bf(u0.z - v0.z); t[3] = f2bf(u0.w - v0.w);
        t[4] = f2bf(u1.x - v1.x); t[5] = f2bf(u1.y - v1.y);
        t[6] = f2bf(u1.z - v1.z); t[7] = f2bf(u1.w - v1.w);
        a1[kt] = t;
    }
#pragma unroll
    for (int kt = 8; kt < 12; ++kt) {
        const float* base = (kt < 10) ? (ef + (size_t)er * 32 + (kt - 8) * 16 + half)
                                      : (df + (size_t)er * 32 + (kt - 10) * 16 + half);
        float4 u0 = *(const float4*)(base);
        float4 u1 = *(const float4*)(base + 4);
        short8 t;
        t[0] = f2bf(u0.x); t[1] = f2bf(u0.y); t[2] = f2bf(u0.z); t[3] = f2bf(u0.w);
        t[4] = f2bf(u1.x); t[5] = f2bf(u1.y); t[6] = f2bf(u1.z); t[7] = f2bf(u1.w);
        a1[kt] = t;
    }

    const short* gw = g_wp + (size_t)ii * 81920;

    f32x16 m0, m1, c0, c1;
    run_path(gw,         b0m, wp, hs, a1, tid, lane, rt, cg, m0, m1);   // msg
    run_path(gw + 40960, b0a, wp, hs, a1, tid, lane, rt, cg, c0, c1);   // att

    // ---- combine + scatter
#pragma unroll
    for (int ct = 0; ct < 2; ++ct) {
        const int col = cg * 64 + ct * 32 + (lane & 31);
        const float bm = b1m[col], ba = b1a[col];
        f32x16 mv = ct ? m1 : m0;
        f32x16 av = ct ? c1 : c0;
#pragma unroll
        for (int reg = 0; reg < 16; ++reg) {
            const int row = (reg & 3) + 8 * (reg >> 2) + 4 * (lane >> 5);
            const float val = (mv[reg] + bm) * sigm(av[reg] + ba);
            atomicAdd(state_msg + (size_t)sdst[rt * 32 + row] * D + col, val);
        }
    }
}

// ---------------- LSTM cell over nodes (unchanged fp32) ----------------
__global__ __launch_bounds__(256)
void lstm_kernel(const float4* __restrict__ x4g, float* __restrict__ hbuf,
                 float* __restrict__ cbuf,
                 const float* __restrict__ wih, const float* __restrict__ whh,
                 const float* __restrict__ bih, const float* __restrict__ bhh) {
    __shared__ float4 s_x[TN][D / 4];
    __shared__ float4 s_h[TN][D / 4];
    const int t  = threadIdx.x;
    const int n0 = blockIdx.x * TN;
    const float4* h4g = (const float4*)hbuf;

#pragma unroll
    for (int i = 0; i < 4; ++i) {
        const int idx = t + i * 256;
        const int n = idx >> 5, cc = idx & 31;
        float4 vx = make_float4(0.f, 0.f, 0.f, 0.f), vh = vx;
        if (n0 + n < N) {
            vx = x4g[(size_t)(n0 + n) * 32 + cc];
            vh = h4g[(size_t)(n0 + n) * 32 + cc];
        }
        s_x[n][cc] = vx;
        s_h[n][cc] = vh;
    }
    __syncthreads();

    const int tc = t & 63;
    const int nb = (t >> 6) * 8;

    float acc[4][2][8];
#pragma unroll
    for (int q = 0; q < 4; ++q)
#pragma unroll
        for (int cc = 0; cc < 2; ++cc)
#pragma unroll
            for (int nn = 0; nn < 8; ++nn) acc[q][cc][nn] = 0.f;

#pragma unroll 1
    for (int k4 = 0; k4 < 32; ++k4) {
        float4 v[8];
#pragma unroll
        for (int nn = 0; nn < 8; ++nn) v[nn] = s_x[nb + nn][k4];
#pragma unroll
        for (int q = 0; q < 4; ++q)
#pragma unroll
            for (int cc = 0; cc < 2; ++cc) {
                const float4 w = *(const float4*)&wih[(size_t)(q * 128 + tc * 2 + cc) * D + k4 * 4];
#pragma unroll
                for (int nn = 0; nn < 8; ++nn) {
                    acc[q][cc][nn] = fmaf(v[nn].x, w.x, acc[q][cc][nn]);
                    acc[q][cc][nn] = fmaf(v[nn].y, w.y, acc[q][cc][nn]);
                    acc[q][cc][nn] = fmaf(v[nn].z, w.z, acc[q][cc][nn]);
                    acc[q][cc][nn] = fmaf(v[nn].w, w.w, acc[q][cc][nn]);
                }
            }
#pragma unroll
        for (int nn = 0; nn < 8; ++nn) v[nn] = s_h[nb + nn][k4];
#pragma unroll
        for (int q = 0; q < 4; ++q)
#pragma unroll
            for (int cc = 0; cc < 2; ++cc) {
                const float4 w = *(const float4*)&whh[(size_t)(q * 128 + tc * 2 + cc) * D + k4 * 4];
#pragma unroll
                for (int nn = 0; nn < 8; ++nn) {
                    acc[q][cc][nn] = fmaf(v[nn].x, w.x, acc[q][cc][nn]);
                    acc[q][cc][nn] = fmaf(v[nn].y, w.y, acc[q][cc][nn]);
                    acc[q][cc][nn] = fmaf(v[nn].z, w.z, acc[q][cc][nn]);
                    acc[q][cc][nn] = fmaf(v[nn].w, w.w, acc[q][cc][nn]);
                }
            }
    }

#pragma unroll
    for (int cc = 0; cc < 2; ++cc) {
        const int col = tc * 2 + cc;
        const float bi = bih[col]       + bhh[col];
        const float bf = bih[128 + col] + bhh[128 + col];
        const float bg = bih[256 + col] + bhh[256 + col];
        const float bo = bih[384 + col] + bhh[384 + col];
#pragma unroll
        for (int nn = 0; nn < 8; ++nn) {
            const int n = n0 + nb + nn;
            if (n < N) {
                const float gi = acc[0][cc][nn] + bi;
                const float gf = acc[1][cc][nn] + bf;
                const float gg = acc[2][cc][nn] + bg;
                const float go = acc[3][cc][nn] + bo;
                float* cp = cbuf + (size_t)n * D + col;
                const float c2 = sigm(gf) * (*cp) + sigm(gi) * tanhf(gg);
                const float h2 = sigm(go) * tanhf(c2);
                *cp = c2;
                hbuf[(size_t)n * D + col] = h2;
            }
        }
    }
}

extern "C" void kernel_launch(void* const* d_in, const int* in_sizes, int n_in,
                              void* d_out, int out_size, void* d_ws, size_t ws_size,
                              hipStream_t stream) {
    const float* node_feat   = (const float*)d_in[0];
    const float* node_feat_c = (const float*)d_in[1];
    const int*   edge        = (const int*)d_in[2];
    const float* edge_feat   = (const float*)d_in[3];
    const float* dist_feat   = (const float*)d_in[4];
    const float* msg_w0 = (const float*)d_in[5];
    const float* msg_b0 = (const float*)d_in[6];
    const float* msg_w1 = (const float*)d_in[7];
    const float* msg_b1 = (const float*)d_in[8];
    const float* att_w0 = (const float*)d_in[9];
    const float* att_b0 = (const float*)d_in[10];
    const float* att_w1 = (const float*)d_in[11];
    const float* att_b1 = (const float*)d_in[12];
    const float* lstm_wih = (const float*)d_in[13];
    const float* lstm_whh = (const float*)d_in[14];
    const float* lstm_bih = (const float*)d_in[15];
    const float* lstm_bhh = (const float*)d_in[16];

    float* state     = (float*)d_out;
    float* state_c   = (float*)d_ws;
    float* state_msg = (float*)d_ws + (size_t)N * D;

    pack_kernel<<<640, 256, 0, stream>>>(msg_w0, att_w0, msg_w1, att_w1);

    init_kernel<<<2048, 256, 0, stream>>>((const float4*)node_feat, (const float4*)node_feat_c,
                                          (float4*)state, (float4*)state_c);

    for (int ii = 0; ii < 2; ++ii) {
        relu_zero_kernel<<<2048, 256, 0, stream>>>((float4*)state, (float4*)state_msg, ii > 0 ? 1 : 0);

        edge_mfma<<<M / TE, 256, 0, stream>>>(
            state, edge, edge_feat, dist_feat, ii,
            msg_b0 + (size_t)ii * D, msg_b1 + (size_t)ii * D,
            att_b0 + (size_t)ii * D, att_b1 + (size_t)ii * D,
            state_msg);

        lstm_kernel<<<(N + TN - 1) / TN, 256, 0, stream>>>(
            (const float4*)state_msg, state, state_c,
            lstm_wih + (size_t)ii * 4 * D * D, lstm_whh + (size_t)ii * 4 * D * D,
            lstm_bih + (size_t)ii * 4 * D,     lstm_bhh + (size_t)ii * 4 * D);
    }
}

// Round 3
// 1141.924 us; speedup vs baseline: 5.0365x; 2.1014x over previous
//
#include <hip/hip_runtime.h>

constexpr int N  = 50000;
constexpr int M  = 800000;
constexpr int D  = 128;
constexpr int IN = 192;   // D + EF + DF
constexpr int TE = 64;    // edges per block (edge kernel)

typedef __attribute__((ext_vector_type(8)))  short short8;
typedef __attribute__((ext_vector_type(16))) float f32x16;

// packed bf16 edge weights: 2 layers x [W0m(3072 s8)|W1m(2048)|W0a(3072)|W1a(2048)] = 10240 short8/layer
__device__ __align__(16) short g_wp[163840];
// packed bf16 LSTM weights: 2 layers x 256k x 512col frag order = 131072 shorts/layer
__device__ __align__(16) short g_lw[262144];
// packed bf16 [ef|df] rows: M x 64
__device__ __align__(16) short g_efdf[(size_t)M * 64];

__device__ __forceinline__ float sigm(float x) { return 1.0f / (1.0f + __expf(-x)); }

__device__ __forceinline__ short f2bf(float f) {
    unsigned u = __builtin_bit_cast(unsigned, f);
    u = (u + 0x7FFFu + ((u >> 16) & 1u)) >> 16;   // RNE
    return (short)u;
}

// ---------------- packs ----------------
// edge weights -> MFMA B-fragment order: frag f=(kt*4+ct)*64+lane, elem e:
// B[k=kt*16+(lane>>5)*8+e][col=ct*32+(lane&31)]
__global__ void pack_edge(const float* __restrict__ w0m, const float* __restrict__ w0a,
                          const float* __restrict__ w1m, const float* __restrict__ w1a) {
    int gid = blockIdx.x * 256 + threadIdx.x;          // 0..163839
    int ii = gid / 81920;
    int r  = gid % 81920;
    int p  = r / 40960;  r %= 40960;
    int which = (r >= 24576) ? 1 : 0;
    int r2 = which ? r - 24576 : r;
    int e    = r2 & 7;
    int f    = r2 >> 3;
    int lane = f & 63;
    int ktct = f >> 6;
    int ct = ktct & 3, kt = ktct >> 2;
    int k   = kt * 16 + ((lane >> 5) << 3) + e;
    int col = ct * 32 + (lane & 31);
    const float* w0 = p ? w0a : w0m;
    const float* w1 = p ? w1a : w1m;
    float v = which ? w1[((size_t)ii * D + k) * D + col]
                    : w0[((size_t)ii * IN + k) * D + col];
    g_wp[gid] = f2bf(v);
}

// LSTM weights: B[k][col] = (k<128 ? wih[col][k] : whh[col][k-128]), frag (kt*16+cf)*64+lane
__global__ void pack_lstm(const float* __restrict__ wih, const float* __restrict__ whh) {
    int gid = blockIdx.x * 256 + threadIdx.x;          // 0..262143
    int ii = gid >> 17;
    int r  = gid & 131071;
    int e = r & 7, f = r >> 3;
    int lane = f & 63, rest = f >> 6;
    int cf = rest & 15, kt = rest >> 4;
    int col = cf * 32 + (lane & 31);
    int k   = (kt & 7) * 16 + ((lane >> 5) << 3) + e;
    const float* src = (kt < 8) ? wih : whh;
    g_lw[gid] = f2bf(src[((size_t)ii * 512 + col) * D + k]);
}

__global__ void pack_efdf(const float* __restrict__ ef, const float* __restrict__ df) {
    int gid = blockIdx.x * 256 + threadIdx.x;          // 0..6399999
    int e = gid >> 3, c0 = (gid & 7) * 8;
    const float* s = (c0 < 32) ? (ef + (size_t)e * 32 + c0) : (df + (size_t)e * 32 + (c0 - 32));
    float4 u0 = *(const float4*)s, u1 = *(const float4*)(s + 4);
    short8 t;
    t[0] = f2bf(u0.x); t[1] = f2bf(u0.y); t[2] = f2bf(u0.z); t[3] = f2bf(u0.w);
    t[4] = f2bf(u1.x); t[5] = f2bf(u1.y); t[6] = f2bf(u1.z); t[7] = f2bf(u1.w);
    *(short8*)(g_efdf + (size_t)gid * 8) = t;
}

// ---------------- init / relu+zero ----------------
__global__ void init_kernel(const float4* __restrict__ nf, const float4* __restrict__ nfc,
                            float4* __restrict__ state, float4* __restrict__ state_c) {
    const int total = N * D / 4;
    for (int i = blockIdx.x * blockDim.x + threadIdx.x; i < total; i += gridDim.x * blockDim.x) {
        state[i]   = nf[i];
        state_c[i] = nfc[i];
    }
}

__global__ void relu_zero_kernel(float4* __restrict__ state, float4* __restrict__ msg, int do_relu) {
    const int total = N * D / 4;
    const float4 z = make_float4(0.f, 0.f, 0.f, 0.f);
    for (int i = blockIdx.x * blockDim.x + threadIdx.x; i < total; i += gridDim.x * blockDim.x) {
        if (do_relu) {
            float4 v = state[i];
            v.x = fmaxf(v.x, 0.f); v.y = fmaxf(v.y, 0.f);
            v.z = fmaxf(v.z, 0.f); v.w = fmaxf(v.w, 0.f);
            state[i] = v;
        }
        msg[i] = z;
    }
}

// ---------------- edge kernel: chunked dbuf weight pipeline ----------------
// weight stream per layer: 10 chunks x 1024 short8 (16KB): [G1m 0-2 | G2m 3-4 | G1a 5-7 | G2a 8-9]
__device__ __forceinline__ void stage_ld(const short8* __restrict__ gsrc, int gc, short8 g[4], int tid) {
    const short8* p = gsrc + (size_t)gc * 1024;
#pragma unroll
    for (int i = 0; i < 4; ++i) g[i] = p[tid + i * 256];
}
__device__ __forceinline__ void stage_st(short8* wb, int gc, const short8 g[4], int tid) {
    short8* d = wb + (gc & 1) * 1024;
#pragma unroll
    for (int i = 0; i < 4; ++i) d[tid + i * 256] = g[i];
}

template<int BASE>
__device__ __forceinline__ void gemm12(const short8* __restrict__ gsrc, short8* wb,
                                       const short8 a1[12], int tid, int lane, int cg,
                                       f32x16& o0, f32x16& o1) {
    f32x16 acc0 = {}, acc1 = {};
#pragma unroll
    for (int c = 0; c < 3; ++c) {
        const int gc = BASE + c;
        short8 g[4];
        if (gc + 1 < 10) stage_ld(gsrc, gc + 1, g, tid);
        const short8* buf = wb + (gc & 1) * 1024;
#pragma unroll
        for (int kl = 0; kl < 4; ++kl) {
            short8 b0 = buf[(kl * 4 + cg * 2 + 0) * 64 + lane];
            short8 b1 = buf[(kl * 4 + cg * 2 + 1) * 64 + lane];
            acc0 = __builtin_amdgcn_mfma_f32_32x32x16_bf16(a1[c * 4 + kl], b0, acc0, 0, 0, 0);
            acc1 = __builtin_amdgcn_mfma_f32_32x32x16_bf16(a1[c * 4 + kl], b1, acc1, 0, 0, 0);
        }
        if (gc + 1 < 10) stage_st(wb, gc + 1, g, tid);
        __syncthreads();
    }
    o0 = acc0; o1 = acc1;
}

template<int BASE>
__device__ __forceinline__ void gemm8(const short8* __restrict__ gsrc, short8* wb,
                                      const short (*hsr)[136], int tid, int lane, int cg, int half,
                                      f32x16& o0, f32x16& o1) {
    f32x16 acc0 = {}, acc1 = {};
#pragma unroll
    for (int c = 0; c < 2; ++c) {
        const int gc = BASE + c;
        short8 g[4];
        if (gc + 1 < 10) stage_ld(gsrc, gc + 1, g, tid);
        const short8* buf = wb + (gc & 1) * 1024;
#pragma unroll
        for (int kl = 0; kl < 4; ++kl) {
            const int kt = c * 4 + kl;
            short8 a2 = *(const short8*)&hsr[lane & 31][kt * 16 + half];
            short8 b0 = buf[(kl * 4 + cg * 2 + 0) * 64 + lane];
            short8 b1 = buf[(kl * 4 + cg * 2 + 1) * 64 + lane];
            acc0 = __builtin_amdgcn_mfma_f32_32x32x16_bf16(a2, b0, acc0, 0, 0, 0);
            acc1 = __builtin_amdgcn_mfma_f32_32x32x16_bf16(a2, b1, acc1, 0, 0, 0);
        }
        if (gc + 1 < 10) stage_st(wb, gc + 1, g, tid);
        __syncthreads();
    }
    o0 = acc0; o1 = acc1;
}

__device__ __forceinline__ void hwrite(short (*hsr)[136], const f32x16& a0, const f32x16& a1v,
                                       const float* __restrict__ b0, int lane, int cg) {
#pragma unroll
    for (int ct = 0; ct < 2; ++ct) {
        const int col = cg * 64 + ct * 32 + (lane & 31);
        const float bv = b0[col];
        f32x16 a = ct ? a1v : a0;
#pragma unroll
        for (int reg = 0; reg < 16; ++reg) {
            const int row = (reg & 3) + 8 * (reg >> 2) + 4 * (lane >> 5);
            hsr[row][col] = f2bf(fmaxf(a[reg] + bv, 0.f));
        }
    }
}

__global__ __launch_bounds__(256, 3)
void edge_mfma(const float* __restrict__ state, const int* __restrict__ edge,
               int ii,
               const float* __restrict__ b0m, const float* __restrict__ b1m,
               const float* __restrict__ b0a, const float* __restrict__ b1a,
               float* __restrict__ state_msg) {
    __shared__ short8 wb[2048];          // 32 KB dbuf weight chunks
    __shared__ short  hs[2][32][136];    // 17.4 KB hidden
    __shared__ int    sdst[TE];

    const int tid  = threadIdx.x;
    const int lane = tid & 63;
    const int w    = tid >> 6;
    const int rt   = w >> 1, cg = w & 1;
    const int e0   = blockIdx.x * TE;

    if (tid < TE) sdst[tid] = edge[(e0 + tid) * 2 + 1];

    // ---- gather A1 fragments straight into registers
    const int er   = e0 + rt * 32 + (lane & 31);
    const int half = (lane >> 5) << 3;
    const int s  = edge[er * 2];
    const int d2 = edge[er * 2 + 1];
    const float* srow = state + (size_t)s  * D;
    const float* drow = state + (size_t)d2 * D;
    short8 a1[12];
#pragma unroll
    for (int kt = 0; kt < 8; ++kt) {
        const int k0 = kt * 16 + half;
        float4 u0 = *(const float4*)(srow + k0);
        float4 u1 = *(const float4*)(srow + k0 + 4);
        float4 v0 = *(const float4*)(drow + k0);
        float4 v1 = *(const float4*)(drow + k0 + 4);
        short8 t;
        t[0] = f2bf(u0.x - v0.x); t[1] = f2bf(u0.y - v0.y);
        t[2] = f2bf(u0.z - v0.z); t[3] = f2bf(u0.w - v0.w);
        t[4] = f2bf(u1.x - v1.x); t[5] = f2bf(u1.y - v1.y);
        t[6] = f2bf(u1.z - v1.z); t[7] = f2bf(u1.w - v1.w);
        a1[kt] = t;
    }
#pragma unroll
    for (int kt = 8; kt < 12; ++kt)
        a1[kt] = *(const short8*)(g_efdf + (size_t)er * 64 + (kt - 8) * 16 + half);

    const short8* gsrc = (const short8*)(g_wp + (size_t)ii * 81920);

    // prologue: stage chunk 0
    {
        short8 g[4];
        stage_ld(gsrc, 0, g, tid);
        stage_st(wb, 0, g, tid);
        __syncthreads();
    }

    f32x16 t0, t1, m0, m1, c0, c1;
    // msg path
    gemm12<0>(gsrc, (short8*)wb, a1, tid, lane, cg, t0, t1);
    hwrite(hs[rt], t0, t1, b0m, lane, cg);
    __syncthreads();
    gemm8<3>(gsrc, (short8*)wb, hs[rt], tid, lane, cg, half, m0, m1);
    // att path
    gemm12<5>(gsrc, (short8*)wb, a1, tid, lane, cg, t0, t1);
    hwrite(hs[rt], t0, t1, b0a, lane, cg);
    __syncthreads();
    gemm8<8>(gsrc, (short8*)wb, hs[rt], tid, lane, cg, half, c0, c1);

    // ---- combine + scatter
#pragma unroll
    for (int ct = 0; ct < 2; ++ct) {
        const int col = cg * 64 + ct * 32 + (lane & 31);
        const float bm = b1m[col], ba = b1a[col];
        f32x16 mv = ct ? m1 : m0;
        f32x16 av = ct ? c1 : c0;
#pragma unroll
        for (int reg = 0; reg < 16; ++reg) {
            const int row = (reg & 3) + 8 * (reg >> 2) + 4 * (lane >> 5);
            const float val = (mv[reg] + bm) * sigm(av[reg] + ba);
            atomicAdd(state_msg + (size_t)sdst[rt * 32 + row] * D + col, val);
        }
    }
}

// ---------------- LSTM: bf16 MFMA, 32 nodes/block, wave w -> cols w*32..+31 of each gate ----------------
__global__ __launch_bounds__(256, 4)
void lstm_mfma(const float* __restrict__ x, float* __restrict__ hbuf, float* __restrict__ cbuf,
               int ii,
               const float* __restrict__ bih, const float* __restrict__ bhh) {
    __shared__ short8 wb[2048];          // 32 KB dbuf (chunk = 16k x 512col = 1024 s8)
    const int tid  = threadIdx.x;
    const int lane = tid & 63;
    const int w    = tid >> 6;
    const int n0   = blockIdx.x * 32;
    const int half = (lane >> 5) << 3;
    const int nl   = lane & 31;
    const int nld  = min(n0 + nl, N - 1);

    const short8* gsrc = (const short8*)(g_lw + (size_t)ii * 131072);

    // prologue: stage chunk 0
    {
        short8 g[4];
#pragma unroll
        for (int i = 0; i < 4; ++i) g[i] = gsrc[tid + i * 256];
#pragma unroll
        for (int i = 0; i < 4; ++i) wb[tid + i * 256] = g[i];
        __syncthreads();
    }

    f32x16 acc[4] = {};
#pragma unroll
    for (int kt = 0; kt < 16; ++kt) {
        // A-frag: rows = nodes, k = kt*16 + half + e  (x for kt<8, h for kt>=8)
        const float* srow = (kt < 8) ? (x + (size_t)nld * D + kt * 16 + half)
                                     : (hbuf + (size_t)nld * D + (kt - 8) * 16 + half);
        float4 u0 = *(const float4*)(srow);
        float4 u1 = *(const float4*)(srow + 4);
        short8 a;
        a[0] = f2bf(u0.x); a[1] = f2bf(u0.y); a[2] = f2bf(u0.z); a[3] = f2bf(u0.w);
        a[4] = f2bf(u1.x); a[5] = f2bf(u1.y); a[6] = f2bf(u1.z); a[7] = f2bf(u1.w);

        short8 g[4];
        if (kt + 1 < 16) {
            const short8* p = gsrc + (size_t)(kt + 1) * 1024;
#pragma unroll
            for (int i = 0; i < 4; ++i) g[i] = p[tid + i * 256];
        }
        const short8* buf = wb + (kt & 1) * 1024;
#pragma unroll
        for (int q = 0; q < 4; ++q) {
            short8 b = buf[(q * 4 + w) * 64 + lane];
            acc[q] = __builtin_amdgcn_mfma_f32_32x32x16_bf16(a, b, acc[q], 0, 0, 0);
        }
        if (kt + 1 < 16) {
            short8* d = wb + ((kt + 1) & 1) * 1024;
#pragma unroll
            for (int i = 0; i < 4; ++i) d[tid + i * 256] = g[i];
        }
        __syncthreads();
    }

    // epilogue: wave-local gates
    const int col = (w << 5) + nl;                 // 0..127 within each gate
    const float bi = bih[col]       + bhh[col];
    const float bf = bih[128 + col] + bhh[128 + col];
    const float bg = bih[256 + col] + bhh[256 + col];
    const float bo = bih[384 + col] + bhh[384 + col];
#pragma unroll
    for (int reg = 0; reg < 16; ++reg) {
        const int nn = (reg & 3) + 8 * (reg >> 2) + 4 * (lane >> 5);
        const int n = n0 + nn;
        if (n < N) {
            const float gi = acc[0][reg] + bi;
            const float gf = acc[1][reg] + bf;
            const float gg = acc[2][reg] + bg;
            const float go = acc[3][reg] + bo;
            float* cp = cbuf + (size_t)n * D + col;
            const float c2 = sigm(gf) * (*cp) + sigm(gi) * tanhf(gg);
            const float h2 = sigm(go) * tanhf(c2);
            *cp = c2;
            hbuf[(size_t)n * D + col] = h2;
        }
    }
}

extern "C" void kernel_launch(void* const* d_in, const int* in_sizes, int n_in,
                              void* d_out, int out_size, void* d_ws, size_t ws_size,
                              hipStream_t stream) {
    const float* node_feat   = (const float*)d_in[0];
    const float* node_feat_c = (const float*)d_in[1];
    const int*   edge        = (const int*)d_in[2];
    const float* edge_feat   = (const float*)d_in[3];
    const float* dist_feat   = (const float*)d_in[4];
    const float* msg_w0 = (const float*)d_in[5];
    const float* msg_b0 = (const float*)d_in[6];
    const float* msg_w1 = (const float*)d_in[7];
    const float* msg_b1 = (const float*)d_in[8];
    const float* att_w0 = (const float*)d_in[9];
    const float* att_b0 = (const float*)d_in[10];
    const float* att_w1 = (const float*)d_in[11];
    const float* att_b1 = (const float*)d_in[12];
    const float* lstm_wih = (const float*)d_in[13];
    const float* lstm_whh = (const float*)d_in[14];
    const float* lstm_bih = (const float*)d_in[15];
    const float* lstm_bhh = (const float*)d_in[16];

    float* state     = (float*)d_out;
    float* state_c   = (float*)d_ws;
    float* state_msg = (float*)d_ws + (size_t)N * D;

    pack_edge<<<640, 256, 0, stream>>>(msg_w0, att_w0, msg_w1, att_w1);
    pack_lstm<<<1024, 256, 0, stream>>>(lstm_wih, lstm_whh);
    pack_efdf<<<25000, 256, 0, stream>>>(edge_feat, dist_feat);

    init_kernel<<<2048, 256, 0, stream>>>((const float4*)node_feat, (const float4*)node_feat_c,
                                          (float4*)state, (float4*)state_c);

    for (int ii = 0; ii < 2; ++ii) {
        relu_zero_kernel<<<2048, 256, 0, stream>>>((float4*)state, (float4*)state_msg, ii > 0 ? 1 : 0);

        edge_mfma<<<M / TE, 256, 0, stream>>>(
            state, edge, ii,
            msg_b0 + (size_t)ii * D, msg_b1 + (size_t)ii * D,
            att_b0 + (size_t)ii * D, att_b1 + (size_t)ii * D,
            state_msg);

        lstm_mfma<<<(N + 31) / 32, 256, 0, stream>>>(
            state_msg, state, state_c, ii,
            lstm_bih + (size_t)ii * 4 * D, lstm_bhh + (size_t)ii * 4 * D);
    }
}

// Round 4
// 967.655 us; speedup vs baseline: 5.9436x; 1.1801x over previous
//
#include <hip/hip_runtime.h>

constexpr int N  = 50000;
constexpr int M  = 800000;
constexpr int D  = 128;
constexpr int IN = 192;   // D + EF + DF
constexpr int TE = 64;    // edges per block (edge kernel)

typedef __attribute__((ext_vector_type(4)))  short short4v;
typedef __attribute__((ext_vector_type(8)))  short short8;
typedef __attribute__((ext_vector_type(16))) float f32x16;

// packed bf16 edge weights: 2 layers x [W0m(3072 s8)|W1m(2048)|W0a(3072)|W1a(2048)]
__device__ __align__(16) short g_wp[163840];
// packed bf16 LSTM weights
__device__ __align__(16) short g_lw[262144];
// packed bf16 [ef|df] rows, in SORTED edge order: M x 64
__device__ __align__(16) short g_efdf[(size_t)M * 64];
// bf16 shadow of state (edge-input view), rewritten per layer
__device__ __align__(16) short g_sbf[(size_t)N * D];
// sort machinery
__device__ int g_cnt[N];     // histogram -> exclusive offsets -> scatter cursors
__device__ int g_ssrc[M];    // src, sorted by dst
__device__ int g_sdst[M];    // dst, sorted
__device__ int g_pos[M];     // original edge -> sorted position

__device__ __forceinline__ float sigm(float x) { return 1.0f / (1.0f + __expf(-x)); }

__device__ __forceinline__ short f2bf(float f) {
    unsigned u = __builtin_bit_cast(unsigned, f);
    u = (u + 0x7FFFu + ((u >> 16) & 1u)) >> 16;   // RNE
    return (short)u;
}
__device__ __forceinline__ float bf2f(short s) {
    return __builtin_bit_cast(float, ((unsigned)(unsigned short)s) << 16);
}

// ---------------- sort-by-dst (counting sort, per call) ----------------
__global__ void zero_cnt_kernel() {
    for (int i = blockIdx.x * 256 + threadIdx.x; i < N; i += gridDim.x * 256) g_cnt[i] = 0;
}
__global__ void hist_kernel(const int* __restrict__ edge) {
    int e = blockIdx.x * 256 + threadIdx.x;
    if (e < M) atomicAdd(&g_cnt[edge[e * 2 + 1]], 1);
}
__global__ void scan_kernel() {   // single block, 256 threads
    __shared__ int partial[256];
    const int t = threadIdx.x;
    const int CH = (N + 255) / 256;
    const int base = t * CH;
    int sum = 0;
    for (int i = 0; i < CH; ++i) { int idx = base + i; if (idx < N) sum += g_cnt[idx]; }
    partial[t] = sum;
    __syncthreads();
    if (t == 0) { int acc = 0; for (int i = 0; i < 256; ++i) { int x = partial[i]; partial[i] = acc; acc += x; } }
    __syncthreads();
    int run = partial[t];
    for (int i = 0; i < CH; ++i) {
        int idx = base + i;
        if (idx < N) { int c = g_cnt[idx]; g_cnt[idx] = run; run += c; }
    }
}
__global__ void scatter_kernel(const int* __restrict__ edge) {
    int e = blockIdx.x * 256 + threadIdx.x;
    if (e < M) {
        const int s = edge[e * 2], d = edge[e * 2 + 1];
        const int p = atomicAdd(&g_cnt[d], 1);
        g_pos[e]  = p;
        g_ssrc[p] = s;
        g_sdst[p] = d;
    }
}

// ---------------- packs ----------------
__global__ void pack_edge(const float* __restrict__ w0m, const float* __restrict__ w0a,
                          const float* __restrict__ w1m, const float* __restrict__ w1a) {
    int gid = blockIdx.x * 256 + threadIdx.x;          // 0..163839
    int ii = gid / 81920;
    int r  = gid % 81920;
    int p  = r / 40960;  r %= 40960;
    int which = (r >= 24576) ? 1 : 0;
    int r2 = which ? r - 24576 : r;
    int e    = r2 & 7;
    int f    = r2 >> 3;
    int lane = f & 63;
    int ktct = f >> 6;
    int ct = ktct & 3, kt = ktct >> 2;
    int k   = kt * 16 + ((lane >> 5) << 3) + e;
    int col = ct * 32 + (lane & 31);
    const float* w0 = p ? w0a : w0m;
    const float* w1 = p ? w1a : w1m;
    float v = which ? w1[((size_t)ii * D + k) * D + col]
                    : w0[((size_t)ii * IN + k) * D + col];
    g_wp[gid] = f2bf(v);
}

__global__ void pack_lstm(const float* __restrict__ wih, const float* __restrict__ whh) {
    int gid = blockIdx.x * 256 + threadIdx.x;          // 0..262143
    int ii = gid >> 17;
    int r  = gid & 131071;
    int e = r & 7, f = r >> 3;
    int lane = f & 63, rest = f >> 6;
    int cf = rest & 15, kt = rest >> 4;
    int col = cf * 32 + (lane & 31);
    int k   = (kt & 7) * 16 + ((lane >> 5) << 3) + e;
    const float* src = (kt < 8) ? wih : whh;
    g_lw[gid] = f2bf(src[((size_t)ii * 512 + col) * D + k]);
}

// ef/df -> bf16, written to SORTED position
__global__ void pack_efdf(const float* __restrict__ ef, const float* __restrict__ df) {
    int gid = blockIdx.x * 256 + threadIdx.x;          // 0..6399999
    int e = gid >> 3, c0 = (gid & 7) * 8;
    const float* s = (c0 < 32) ? (ef + (size_t)e * 32 + c0) : (df + (size_t)e * 32 + (c0 - 32));
    float4 u0 = *(const float4*)s, u1 = *(const float4*)(s + 4);
    short8 t;
    t[0] = f2bf(u0.x); t[1] = f2bf(u0.y); t[2] = f2bf(u0.z); t[3] = f2bf(u0.w);
    t[4] = f2bf(u1.x); t[5] = f2bf(u1.y); t[6] = f2bf(u1.z); t[7] = f2bf(u1.w);
    const size_t pos = (size_t)g_pos[e];
    *(short8*)(g_efdf + pos * 64 + (size_t)(gid & 7) * 8) = t;
}

// ---------------- init / per-layer prep ----------------
__global__ void init_kernel(const float4* __restrict__ nf, const float4* __restrict__ nfc,
                            float4* __restrict__ state, float4* __restrict__ state_c) {
    const int total = N * D / 4;
    for (int i = blockIdx.x * blockDim.x + threadIdx.x; i < total; i += gridDim.x * blockDim.x) {
        state[i]   = nf[i];
        state_c[i] = nfc[i];
    }
}

// optionally relu state in place, emit bf16 shadow, zero state_msg
__global__ void prep_kernel(float4* __restrict__ state, float4* __restrict__ msg, int do_relu) {
    const int total = N * D / 4;
    const float4 z = make_float4(0.f, 0.f, 0.f, 0.f);
    for (int i = blockIdx.x * blockDim.x + threadIdx.x; i < total; i += gridDim.x * blockDim.x) {
        float4 v = state[i];
        if (do_relu) {
            v.x = fmaxf(v.x, 0.f); v.y = fmaxf(v.y, 0.f);
            v.z = fmaxf(v.z, 0.f); v.w = fmaxf(v.w, 0.f);
            state[i] = v;
        }
        short4v b;
        b[0] = f2bf(v.x); b[1] = f2bf(v.y); b[2] = f2bf(v.z); b[3] = f2bf(v.w);
        *(short4v*)(g_sbf + (size_t)i * 4) = b;
        msg[i] = z;
    }
}

// ---------------- edge kernel: chunked dbuf weight pipeline ----------------
__device__ __forceinline__ void stage_ld(const short8* __restrict__ gsrc, int gc, short8 g[4], int tid) {
    const short8* p = gsrc + (size_t)gc * 1024;
#pragma unroll
    for (int i = 0; i < 4; ++i) g[i] = p[tid + i * 256];
}
__device__ __forceinline__ void stage_st(short8* wb, int gc, const short8 g[4], int tid) {
    short8* d = wb + (gc & 1) * 1024;
#pragma unroll
    for (int i = 0; i < 4; ++i) d[tid + i * 256] = g[i];
}

template<int BASE>
__device__ __forceinline__ void gemm12(const short8* __restrict__ gsrc, short8* wb,
                                       const short8 a1[12], int tid, int lane, int cg,
                                       f32x16& o0, f32x16& o1) {
    f32x16 acc0 = {}, acc1 = {};
#pragma unroll
    for (int c = 0; c < 3; ++c) {
        const int gc = BASE + c;
        short8 g[4];
        if (gc + 1 < 10) stage_ld(gsrc, gc + 1, g, tid);
        const short8* buf = wb + (gc & 1) * 1024;
#pragma unroll
        for (int kl = 0; kl < 4; ++kl) {
            short8 b0 = buf[(kl * 4 + cg * 2 + 0) * 64 + lane];
            short8 b1 = buf[(kl * 4 + cg * 2 + 1) * 64 + lane];
            acc0 = __builtin_amdgcn_mfma_f32_32x32x16_bf16(a1[c * 4 + kl], b0, acc0, 0, 0, 0);
            acc1 = __builtin_amdgcn_mfma_f32_32x32x16_bf16(a1[c * 4 + kl], b1, acc1, 0, 0, 0);
        }
        if (gc + 1 < 10) stage_st(wb, gc + 1, g, tid);
        __syncthreads();
    }
    o0 = acc0; o1 = acc1;
}

template<int BASE>
__device__ __forceinline__ void gemm8(const short8* __restrict__ gsrc, short8* wb,
                                      const short (*hsr)[136], int tid, int lane, int cg, int half,
                                      f32x16& o0, f32x16& o1) {
    f32x16 acc0 = {}, acc1 = {};
#pragma unroll
    for (int c = 0; c < 2; ++c) {
        const int gc = BASE + c;
        short8 g[4];
        if (gc + 1 < 10) stage_ld(gsrc, gc + 1, g, tid);
        const short8* buf = wb + (gc & 1) * 1024;
#pragma unroll
        for (int kl = 0; kl < 4; ++kl) {
            const int kt = c * 4 + kl;
            short8 a2 = *(const short8*)&hsr[lane & 31][kt * 16 + half];
            short8 b0 = buf[(kl * 4 + cg * 2 + 0) * 64 + lane];
            short8 b1 = buf[(kl * 4 + cg * 2 + 1) * 64 + lane];
            acc0 = __builtin_amdgcn_mfma_f32_32x32x16_bf16(a2, b0, acc0, 0, 0, 0);
            acc1 = __builtin_amdgcn_mfma_f32_32x32x16_bf16(a2, b1, acc1, 0, 0, 0);
        }
        if (gc + 1 < 10) stage_st(wb, gc + 1, g, tid);
        __syncthreads();
    }
    o0 = acc0; o1 = acc1;
}

__device__ __forceinline__ void hwrite(short (*hsr)[136], const f32x16& a0, const f32x16& a1v,
                                       const float* __restrict__ b0, int lane, int cg) {
#pragma unroll
    for (int ct = 0; ct < 2; ++ct) {
        const int col = cg * 64 + ct * 32 + (lane & 31);
        const float bv = b0[col];
        f32x16 a = ct ? a1v : a0;
#pragma unroll
        for (int reg = 0; reg < 16; ++reg) {
            const int row = (reg & 3) + 8 * (reg >> 2) + 4 * (lane >> 5);
            hsr[row][col] = f2bf(fmaxf(a[reg] + bv, 0.f));
        }
    }
}

__global__ __launch_bounds__(256, 3)
void edge_mfma(int ii,
               const float* __restrict__ b0m, const float* __restrict__ b1m,
               const float* __restrict__ b0a, const float* __restrict__ b1a,
               float* __restrict__ state_msg) {
    __shared__ short8 wb[2048];          // 32 KB dbuf weight chunks; reused as f32 val tile
    __shared__ short  hs[2][32][136];    // 17.4 KB hidden
    __shared__ int    sdst[TE];

    const int tid  = threadIdx.x;
    const int lane = tid & 63;
    const int w    = tid >> 6;
    const int rt   = w >> 1, cg = w & 1;
    const int e0   = blockIdx.x * TE;

    if (tid < TE) sdst[tid] = g_sdst[e0 + tid];

    // ---- gather A1 fragments from bf16 shadow (sorted edge order)
    const int er   = e0 + rt * 32 + (lane & 31);
    const int half = (lane >> 5) << 3;
    const int s  = g_ssrc[er];
    const int d2 = g_sdst[er];
    const short* srow = g_sbf + (size_t)s  * D;
    const short* drow = g_sbf + (size_t)d2 * D;
    short8 a1[12];
#pragma unroll
    for (int kt = 0; kt < 8; ++kt) {
        const int k0 = kt * 16 + half;
        short8 sv = *(const short8*)(srow + k0);
        short8 dv = *(const short8*)(drow + k0);
        short8 t;
#pragma unroll
        for (int e = 0; e < 8; ++e) t[e] = f2bf(bf2f(sv[e]) - bf2f(dv[e]));
        a1[kt] = t;
    }
#pragma unroll
    for (int kt = 8; kt < 12; ++kt)
        a1[kt] = *(const short8*)(g_efdf + (size_t)er * 64 + (kt - 8) * 16 + half);

    const short8* gsrc = (const short8*)(g_wp + (size_t)ii * 81920);

    // prologue: stage chunk 0
    {
        short8 g[4];
        stage_ld(gsrc, 0, g, tid);
        stage_st(wb, 0, g, tid);
        __syncthreads();
    }

    f32x16 t0, t1, m0, m1, c0, c1;
    gemm12<0>(gsrc, (short8*)wb, a1, tid, lane, cg, t0, t1);
    hwrite(hs[rt], t0, t1, b0m, lane, cg);
    __syncthreads();
    gemm8<3>(gsrc, (short8*)wb, hs[rt], tid, lane, cg, half, m0, m1);
    gemm12<5>(gsrc, (short8*)wb, a1, tid, lane, cg, t0, t1);
    hwrite(hs[rt], t0, t1, b0a, lane, cg);
    __syncthreads();
    gemm8<8>(gsrc, (short8*)wb, hs[rt], tid, lane, cg, half, c0, c1);

    // ---- combine into LDS f32 tile (reuse wb)
    float (*vt)[D] = (float(*)[D])wb;
#pragma unroll
    for (int ct = 0; ct < 2; ++ct) {
        const int col = cg * 64 + ct * 32 + (lane & 31);
        const float bm = b1m[col], ba = b1a[col];
        f32x16 mv = ct ? m1 : m0;
        f32x16 av = ct ? c1 : c0;
#pragma unroll
        for (int reg = 0; reg < 16; ++reg) {
            const int row = rt * 32 + (reg & 3) + 8 * (reg >> 2) + 4 * (lane >> 5);
            vt[row][col] = (mv[reg] + bm) * sigm(av[reg] + ba);
        }
    }
    __syncthreads();

    // ---- segmented reduction over sorted dst runs: 1 atomic per (run, col)
    const int colr = tid & 127;
    const int rbase = (tid >> 7) * 32;
    float run = 0.f;
    int cur = sdst[rbase];
#pragma unroll 4
    for (int r = 0; r < 32; ++r) {
        const int dd = sdst[rbase + r];
        if (dd != cur) {
            atomicAdd(state_msg + (size_t)cur * D + colr, run);
            run = 0.f; cur = dd;
        }
        run += vt[rbase + r][colr];
    }
    atomicAdd(state_msg + (size_t)cur * D + colr, run);
}

// ---------------- LSTM: bf16 MFMA (unchanged) ----------------
__global__ __launch_bounds__(256, 4)
void lstm_mfma(const float* __restrict__ x, float* __restrict__ hbuf, float* __restrict__ cbuf,
               int ii,
               const float* __restrict__ bih, const float* __restrict__ bhh) {
    __shared__ short8 wb[2048];
    const int tid  = threadIdx.x;
    const int lane = tid & 63;
    const int w    = tid >> 6;
    const int n0   = blockIdx.x * 32;
    const int half = (lane >> 5) << 3;
    const int nl   = lane & 31;
    const int nld  = min(n0 + nl, N - 1);

    const short8* gsrc = (const short8*)(g_lw + (size_t)ii * 131072);

    {
        short8 g[4];
#pragma unroll
        for (int i = 0; i < 4; ++i) g[i] = gsrc[tid + i * 256];
#pragma unroll
        for (int i = 0; i < 4; ++i) wb[tid + i * 256] = g[i];
        __syncthreads();
    }

    f32x16 acc[4] = {};
#pragma unroll
    for (int kt = 0; kt < 16; ++kt) {
        const float* srow = (kt < 8) ? (x + (size_t)nld * D + kt * 16 + half)
                                     : (hbuf + (size_t)nld * D + (kt - 8) * 16 + half);
        float4 u0 = *(const float4*)(srow);
        float4 u1 = *(const float4*)(srow + 4);
        short8 a;
        a[0] = f2bf(u0.x); a[1] = f2bf(u0.y); a[2] = f2bf(u0.z); a[3] = f2bf(u0.w);
        a[4] = f2bf(u1.x); a[5] = f2bf(u1.y); a[6] = f2bf(u1.z); a[7] = f2bf(u1.w);

        short8 g[4];
        if (kt + 1 < 16) {
            const short8* p = gsrc + (size_t)(kt + 1) * 1024;
#pragma unroll
            for (int i = 0; i < 4; ++i) g[i] = p[tid + i * 256];
        }
        const short8* buf = wb + (kt & 1) * 1024;
#pragma unroll
        for (int q = 0; q < 4; ++q) {
            short8 b = buf[(q * 4 + w) * 64 + lane];
            acc[q] = __builtin_amdgcn_mfma_f32_32x32x16_bf16(a, b, acc[q], 0, 0, 0);
        }
        if (kt + 1 < 16) {
            short8* d = wb + ((kt + 1) & 1) * 1024;
#pragma unroll
            for (int i = 0; i < 4; ++i) d[tid + i * 256] = g[i];
        }
        __syncthreads();
    }

    const int col = (w << 5) + nl;
    const float bi = bih[col]       + bhh[col];
    const float bf = bih[128 + col] + bhh[128 + col];
    const float bg = bih[256 + col] + bhh[256 + col];
    const float bo = bih[384 + col] + bhh[384 + col];
#pragma unroll
    for (int reg = 0; reg < 16; ++reg) {
        const int nn = (reg & 3) + 8 * (reg >> 2) + 4 * (lane >> 5);
        const int n = n0 + nn;
        if (n < N) {
            const float gi = acc[0][reg] + bi;
            const float gf = acc[1][reg] + bf;
            const float gg = acc[2][reg] + bg;
            const float go = acc[3][reg] + bo;
            float* cp = cbuf + (size_t)n * D + col;
            const float c2 = sigm(gf) * (*cp) + sigm(gi) * tanhf(gg);
            const float h2 = sigm(go) * tanhf(c2);
            *cp = c2;
            hbuf[(size_t)n * D + col] = h2;
        }
    }
}

extern "C" void kernel_launch(void* const* d_in, const int* in_sizes, int n_in,
                              void* d_out, int out_size, void* d_ws, size_t ws_size,
                              hipStream_t stream) {
    const float* node_feat   = (const float*)d_in[0];
    const float* node_feat_c = (const float*)d_in[1];
    const int*   edge        = (const int*)d_in[2];
    const float* edge_feat   = (const float*)d_in[3];
    const float* dist_feat   = (const float*)d_in[4];
    const float* msg_w0 = (const float*)d_in[5];
    const float* msg_b0 = (const float*)d_in[6];
    const float* msg_w1 = (const float*)d_in[7];
    const float* msg_b1 = (const float*)d_in[8];
    const float* att_w0 = (const float*)d_in[9];
    const float* att_b0 = (const float*)d_in[10];
    const float* att_w1 = (const float*)d_in[11];
    const float* att_b1 = (const float*)d_in[12];
    const float* lstm_wih = (const float*)d_in[13];
    const float* lstm_whh = (const float*)d_in[14];
    const float* lstm_bih = (const float*)d_in[15];
    const float* lstm_bhh = (const float*)d_in[16];

    float* state     = (float*)d_out;
    float* state_c   = (float*)d_ws;
    float* state_msg = (float*)d_ws + (size_t)N * D;

    // sort edges by dst (per call; edge list static across layers)
    zero_cnt_kernel<<<256, 256, 0, stream>>>();
    hist_kernel<<<(M + 255) / 256, 256, 0, stream>>>(edge);
    scan_kernel<<<1, 256, 0, stream>>>();
    scatter_kernel<<<(M + 255) / 256, 256, 0, stream>>>(edge);

    pack_efdf<<<25000, 256, 0, stream>>>(edge_feat, dist_feat);
    pack_edge<<<640, 256, 0, stream>>>(msg_w0, att_w0, msg_w1, att_w1);
    pack_lstm<<<1024, 256, 0, stream>>>(lstm_wih, lstm_whh);

    init_kernel<<<2048, 256, 0, stream>>>((const float4*)node_feat, (const float4*)node_feat_c,
                                          (float4*)state, (float4*)state_c);

    for (int ii = 0; ii < 2; ++ii) {
        prep_kernel<<<2048, 256, 0, stream>>>((float4*)state, (float4*)state_msg, ii > 0 ? 1 : 0);

        edge_mfma<<<M / TE, 256, 0, stream>>>(
            ii,
            msg_b0 + (size_t)ii * D, msg_b1 + (size_t)ii * D,
            att_b0 + (size_t)ii * D, att_b1 + (size_t)ii * D,
            state_msg);

        lstm_mfma<<<(N + 31) / 32, 256, 0, stream>>>(
            state_msg, state, state_c, ii,
            lstm_bih + (size_t)ii * 4 * D, lstm_bhh + (size_t)ii * 4 * D);
    }
}

// Round 6
// 931.400 us; speedup vs baseline: 6.1750x; 1.0389x over previous
//
#include <hip/hip_runtime.h>
#include <hip/hip_bf16.h>

constexpr int N  = 50000;
constexpr int M  = 800000;
constexpr int D  = 128;
constexpr int IN = 192;   // D + EF + DF
constexpr int TE = 64;    // edges per block (edge kernel)
constexpr int NCH = 20;   // 8KB weight chunks per layer
constexpr int NBLK = (N + 255) / 256;   // scan blocks

typedef __attribute__((ext_vector_type(4)))  short short4v;
typedef __attribute__((ext_vector_type(8)))  short short8;
typedef __attribute__((ext_vector_type(16))) float f32x16;

// packed bf16 edge weights: 2 layers x [W0m(3072 s8)|W1m(2048)|W0a(3072)|W1a(2048)]
__device__ __align__(16) short g_wp[163840];
// packed bf16 LSTM weights
__device__ __align__(16) short g_lw[262144];
// packed bf16 [ef|df] rows, in SORTED edge order: M x 64
__device__ __align__(16) short g_efdf[(size_t)M * 64];
// bf16 shadow of state (edge-input view), rewritten per layer
__device__ __align__(16) short g_sbf[(size_t)N * D];
// sort machinery
__device__ int g_cnt[N];       // histogram -> exclusive offsets -> scatter cursors
__device__ int g_part[NBLK];   // scan partials
__device__ int g_ssrc[M];      // src, sorted by dst
__device__ int g_sdst[M];      // dst, sorted
__device__ int g_inv[M];       // sorted position -> original edge

__device__ __forceinline__ float sigm(float x) { return 1.0f / (1.0f + __expf(-x)); }

__device__ __forceinline__ short f2bf(float f) {
    unsigned u = __builtin_bit_cast(unsigned, f);
    u = (u + 0x7FFFu + ((u >> 16) & 1u)) >> 16;   // RNE
    return (short)u;
}
__device__ __forceinline__ float bf2f(short s) {
    return __builtin_bit_cast(float, ((unsigned)(unsigned short)s) << 16);
}
// pack 2 f32 -> u32 of 2 bf16 (lo=a, hi=b) via v_cvt_pk_bf16_f32
__device__ __forceinline__ unsigned pk2(float a, float b) {
    __hip_bfloat162 h = __float22bfloat162_rn(float2{a, b});
    unsigned u;
    __builtin_memcpy(&u, &h, 4);
    return u;
}

// ---------------- sort-by-dst (counting sort, per call) ----------------
__global__ void zero_cnt_kernel() {
    for (int i = blockIdx.x * 256 + threadIdx.x; i < N; i += gridDim.x * 256) g_cnt[i] = 0;
}
__global__ void hist_kernel(const int* __restrict__ edge) {
    int e = blockIdx.x * 256 + threadIdx.x;
    if (e < M) atomicAdd(&g_cnt[edge[e * 2 + 1]], 1);
}
__global__ void scanA_kernel() {   // block sums
    __shared__ int red[256];
    const int t = threadIdx.x;
    const int idx = blockIdx.x * 256 + t;
    red[t] = (idx < N) ? g_cnt[idx] : 0;
    __syncthreads();
#pragma unroll
    for (int s = 128; s > 0; s >>= 1) {
        if (t < s) red[t] += red[t + s];
        __syncthreads();
    }
    if (t == 0) g_part[blockIdx.x] = red[0];
}
__global__ void scanB_kernel() {   // 1 block: exclusive scan of partials
    __shared__ int sh[256];
    const int t = threadIdx.x;
    int v = (t < NBLK) ? g_part[t] : 0;
    sh[t] = v;
    __syncthreads();
    int x = v;
    for (int s = 1; s < 256; s <<= 1) {
        int y = (t >= s) ? sh[t - s] : 0;
        __syncthreads();
        x += y; sh[t] = x;
        __syncthreads();
    }
    if (t < NBLK) g_part[t] = x - v;
}
__global__ void scanC_kernel() {   // per-block exclusive scan + base
    __shared__ int sh[256];
    const int t = threadIdx.x;
    const int idx = blockIdx.x * 256 + t;
    int v = (idx < N) ? g_cnt[idx] : 0;
    sh[t] = v;
    __syncthreads();
    int x = v;
    for (int s = 1; s < 256; s <<= 1) {
        int y = (t >= s) ? sh[t - s] : 0;
        __syncthreads();
        x += y; sh[t] = x;
        __syncthreads();
    }
    if (idx < N) g_cnt[idx] = g_part[blockIdx.x] + x - v;
}
__global__ void scatter_kernel(const int* __restrict__ edge) {
    int e = blockIdx.x * 256 + threadIdx.x;
    if (e < M) {
        const int s = edge[e * 2], d = edge[e * 2 + 1];
        const int p = atomicAdd(&g_cnt[d], 1);
        g_ssrc[p] = s;
        g_sdst[p] = d;
        g_inv[p]  = e;
    }
}

// ---------------- packs ----------------
__global__ void pack_edge(const float* __restrict__ w0m, const float* __restrict__ w0a,
                          const float* __restrict__ w1m, const float* __restrict__ w1a) {
    int gid = blockIdx.x * 256 + threadIdx.x;          // 0..163839
    int ii = gid / 81920;
    int r  = gid % 81920;
    int p  = r / 40960;  r %= 40960;
    int which = (r >= 24576) ? 1 : 0;
    int r2 = which ? r - 24576 : r;
    int e    = r2 & 7;
    int f    = r2 >> 3;
    int lane = f & 63;
    int ktct = f >> 6;
    int ct = ktct & 3, kt = ktct >> 2;
    int k   = kt * 16 + ((lane >> 5) << 3) + e;
    int col = ct * 32 + (lane & 31);
    const float* w0 = p ? w0a : w0m;
    const float* w1 = p ? w1a : w1m;
    float v = which ? w1[((size_t)ii * D + k) * D + col]
                    : w0[((size_t)ii * IN + k) * D + col];
    g_wp[gid] = f2bf(v);
}

__global__ void pack_lstm(const float* __restrict__ wih, const float* __restrict__ whh) {
    int gid = blockIdx.x * 256 + threadIdx.x;          // 0..262143
    int ii = gid >> 17;
    int r  = gid & 131071;
    int e = r & 7, f = r >> 3;
    int lane = f & 63, rest = f >> 6;
    int cf = rest & 15, kt = rest >> 4;
    int col = cf * 32 + (lane & 31);
    int k   = (kt & 7) * 16 + ((lane >> 5) << 3) + e;
    const float* src = (kt < 8) ? wih : whh;
    g_lw[gid] = f2bf(src[((size_t)ii * 512 + col) * D + k]);
}

// ef/df -> bf16, gathered via inverse perm, written CONTIGUOUS in sorted order
__global__ void pack_efdf(const float* __restrict__ ef, const float* __restrict__ df) {
    int gid = blockIdx.x * 256 + threadIdx.x;          // 0..6399999
    int p = gid >> 3, c0 = (gid & 7) * 8;
    const int e = g_inv[p];
    const float* s = (c0 < 32) ? (ef + (size_t)e * 32 + c0) : (df + (size_t)e * 32 + (c0 - 32));
    float4 u0 = *(const float4*)s, u1 = *(const float4*)(s + 4);
    short8 t;
    unsigned* tp = (unsigned*)&t;
    tp[0] = pk2(u0.x, u0.y); tp[1] = pk2(u0.z, u0.w);
    tp[2] = pk2(u1.x, u1.y); tp[3] = pk2(u1.z, u1.w);
    *(short8*)(g_efdf + (size_t)gid * 8) = t;
}

// ---------------- init / per-layer prep ----------------
__global__ void init_kernel(const float4* __restrict__ nf, const float4* __restrict__ nfc,
                            float4* __restrict__ state, float4* __restrict__ state_c) {
    const int total = N * D / 4;
    for (int i = blockIdx.x * blockDim.x + threadIdx.x; i < total; i += gridDim.x * blockDim.x) {
        state[i]   = nf[i];
        state_c[i] = nfc[i];
    }
}

__global__ void prep_kernel(float4* __restrict__ state, float4* __restrict__ msg, int do_relu) {
    const int total = N * D / 4;
    const float4 z = make_float4(0.f, 0.f, 0.f, 0.f);
    for (int i = blockIdx.x * blockDim.x + threadIdx.x; i < total; i += gridDim.x * blockDim.x) {
        float4 v = state[i];
        if (do_relu) {
            v.x = fmaxf(v.x, 0.f); v.y = fmaxf(v.y, 0.f);
            v.z = fmaxf(v.z, 0.f); v.w = fmaxf(v.w, 0.f);
            state[i] = v;
        }
        short4v b;
        unsigned* bp = (unsigned*)&b;
        bp[0] = pk2(v.x, v.y); bp[1] = pk2(v.z, v.w);
        *(short4v*)(g_sbf + (size_t)i * 4) = b;
        msg[i] = z;
    }
}

// ---------------- edge kernel: 8KB-chunk dbuf weight pipeline ----------------
__device__ __forceinline__ void stage_ld(const short8* __restrict__ gsrc, int gc, short8 g[2], int tid) {
    const short8* p = gsrc + (size_t)gc * 512;
    g[0] = p[tid]; g[1] = p[tid + 256];
}
__device__ __forceinline__ void stage_st(short8* wb, int gc, const short8 g[2], int tid) {
    short8* d = wb + (gc & 1) * 512;
    d[tid] = g[0]; d[tid + 256] = g[1];
}

#define MFMA(a, b, c) __builtin_amdgcn_mfma_f32_32x32x16_bf16(a, b, c, 0, 0, 0)

// 6 chunks (12 kt), A from registers
template<int BASE>
__device__ __forceinline__ void gemmA(const short8* __restrict__ gsrc, short8* wb,
                                      const short8 a1[12], int tid, int lane, int cg,
                                      f32x16& o0, f32x16& o1) {
    f32x16 acc0 = {}, acc1 = {};
#pragma unroll
    for (int c = 0; c < 6; ++c) {
        const int gc = BASE + c;
        short8 g[2];
        if (gc + 1 < NCH) stage_ld(gsrc, gc + 1, g, tid);
        const short8* buf = wb + (gc & 1) * 512;
#pragma unroll
        for (int kl = 0; kl < 2; ++kl) {
            short8 b0 = buf[(kl * 4 + cg * 2 + 0) * 64 + lane];
            short8 b1 = buf[(kl * 4 + cg * 2 + 1) * 64 + lane];
            acc0 = MFMA(a1[c * 2 + kl], b0, acc0);
            acc1 = MFMA(a1[c * 2 + kl], b1, acc1);
        }
        if (gc + 1 < NCH) stage_st(wb, gc + 1, g, tid);
        __syncthreads();
    }
    o0 = acc0; o1 = acc1;
}

// 4 chunks (8 kt), A from hidden LDS
template<int BASE>
__device__ __forceinline__ void gemmH(const short8* __restrict__ gsrc, short8* wb,
                                      const short (*hsr)[136], int tid, int lane, int cg, int half,
                                      f32x16& o0, f32x16& o1) {
    f32x16 acc0 = {}, acc1 = {};
#pragma unroll
    for (int c = 0; c < 4; ++c) {
        const int gc = BASE + c;
        short8 g[2];
        if (gc + 1 < NCH) stage_ld(gsrc, gc + 1, g, tid);
        const short8* buf = wb + (gc & 1) * 512;
#pragma unroll
        for (int kl = 0; kl < 2; ++kl) {
            const int kt = c * 2 + kl;
            short8 a2 = *(const short8*)&hsr[lane & 31][kt * 16 + half];
            short8 b0 = buf[(kl * 4 + cg * 2 + 0) * 64 + lane];
            short8 b1 = buf[(kl * 4 + cg * 2 + 1) * 64 + lane];
            acc0 = MFMA(a2, b0, acc0);
            acc1 = MFMA(a2, b1, acc1);
        }
        if (gc + 1 < NCH) stage_st(wb, gc + 1, g, tid);
        __syncthreads();
    }
    o0 = acc0; o1 = acc1;
}

__device__ __forceinline__ void hwrite(short (*hsr)[136], const f32x16& a0, const f32x16& a1v,
                                       const float* __restrict__ b0, int lane, int cg) {
#pragma unroll
    for (int ct = 0; ct < 2; ++ct) {
        const int col = cg * 64 + ct * 32 + (lane & 31);
        const float bv = b0[col];
        f32x16 a = ct ? a1v : a0;
#pragma unroll
        for (int rp = 0; rp < 8; ++rp) {
            const int reg = rp * 2;
            const int row = (reg & 3) + 8 * (reg >> 2) + 4 * (lane >> 5);
            const unsigned pr = pk2(fmaxf(a[reg] + bv, 0.f), fmaxf(a[reg + 1] + bv, 0.f));
            hsr[row][col]     = (short)(pr & 0xFFFF);
            hsr[row + 1][col] = (short)(pr >> 16);
        }
    }
}

__global__ __launch_bounds__(256, 4)
void edge_mfma(int ii,
               const float* __restrict__ b0m, const float* __restrict__ b1m,
               const float* __restrict__ b0a, const float* __restrict__ b1a,
               float* __restrict__ state_msg) {
    // pool: wb 16384 | hs 17408 | sdst 256  = 34048 B  (4 blocks/CU)
    // epilogue reuses [0, 32768) as f32 value tile (sdst at 33792 is safe)
    __shared__ __align__(16) char pool[34048];
    short8* wb = (short8*)pool;
    short (*hs)[32][136] = (short(*)[32][136])(pool + 16384);
    int* sdst = (int*)(pool + 33792);

    const int tid  = threadIdx.x;
    const int lane = tid & 63;
    const int w    = tid >> 6;
    const int rt   = w >> 1, cg = w & 1;
    const int e0   = blockIdx.x * TE;

    if (tid < TE) sdst[tid] = g_sdst[e0 + tid];

    // ---- gather A1 fragments from bf16 shadow (sorted edge order)
    const int er   = e0 + rt * 32 + (lane & 31);
    const int half = (lane >> 5) << 3;
    const int s  = g_ssrc[er];
    const int d2 = g_sdst[er];
    const short* srow = g_sbf + (size_t)s  * D;
    const short* drow = g_sbf + (size_t)d2 * D;
    short8 a1[12];
#pragma unroll
    for (int kt = 0; kt < 8; ++kt) {
        const int k0 = kt * 16 + half;
        short8 sv = *(const short8*)(srow + k0);
        short8 dv = *(const short8*)(drow + k0);
        short8 t;
        unsigned* tp = (unsigned*)&t;
#pragma unroll
        for (int i = 0; i < 4; ++i)
            tp[i] = pk2(bf2f(sv[2 * i])     - bf2f(dv[2 * i]),
                        bf2f(sv[2 * i + 1]) - bf2f(dv[2 * i + 1]));
        a1[kt] = t;
    }
#pragma unroll
    for (int kt = 8; kt < 12; ++kt)
        a1[kt] = *(const short8*)(g_efdf + (size_t)er * 64 + (kt - 8) * 16 + half);

    const short8* gsrc = (const short8*)(g_wp + (size_t)ii * 81920);

    // prologue: stage chunk 0
    {
        short8 g[2];
        stage_ld(gsrc, 0, g, tid);
        stage_st(wb, 0, g, tid);
        __syncthreads();
    }

    f32x16 t0, t1, m0, m1, c0, c1;
    gemmA<0>(gsrc, wb, a1, tid, lane, cg, t0, t1);          // msg GEMM1 (chunks 0-5)
    hwrite(hs[rt], t0, t1, b0m, lane, cg);
    __syncthreads();
    gemmH<6>(gsrc, wb, hs[rt], tid, lane, cg, half, m0, m1); // msg GEMM2 (6-9)
    gemmA<10>(gsrc, wb, a1, tid, lane, cg, t0, t1);          // att GEMM1 (10-15)
    hwrite(hs[rt], t0, t1, b0a, lane, cg);
    __syncthreads();
    gemmH<16>(gsrc, wb, hs[rt], tid, lane, cg, half, c0, c1); // att GEMM2 (16-19)

    // ---- combine into f32 LDS tile overlaying wb+hs
    float (*vt)[D] = (float(*)[D])pool;
#pragma unroll
    for (int ct = 0; ct < 2; ++ct) {
        const int col = cg * 64 + ct * 32 + (lane & 31);
        const float bm = b1m[col], ba = b1a[col];
        f32x16 mv = ct ? m1 : m0;
        f32x16 av = ct ? c1 : c0;
#pragma unroll
        for (int reg = 0; reg < 16; ++reg) {
            const int row = rt * 32 + (reg & 3) + 8 * (reg >> 2) + 4 * (lane >> 5);
            vt[row][col] = (mv[reg] + bm) * sigm(av[reg] + ba);
        }
    }
    __syncthreads();

    // ---- segmented reduction over sorted dst runs: 1 atomic per (run, col)
    const int colr = tid & 127;
    const int rbase = (tid >> 7) * 32;
    float run = 0.f;
    int cur = sdst[rbase];
#pragma unroll 4
    for (int r = 0; r < 32; ++r) {
        const int dd = sdst[rbase + r];
        if (dd != cur) {
            atomicAdd(state_msg + (size_t)cur * D + colr, run);
            run = 0.f; cur = dd;
        }
        run += vt[rbase + r][colr];
    }
    atomicAdd(state_msg + (size_t)cur * D + colr, run);
}

// ---------------- LSTM: bf16 MFMA (unchanged) ----------------
__global__ __launch_bounds__(256, 4)
void lstm_mfma(const float* __restrict__ x, float* __restrict__ hbuf, float* __restrict__ cbuf,
               int ii,
               const float* __restrict__ bih, const float* __restrict__ bhh) {
    __shared__ short8 wb[2048];
    const int tid  = threadIdx.x;
    const int lane = tid & 63;
    const int w    = tid >> 6;
    const int n0   = blockIdx.x * 32;
    const int half = (lane >> 5) << 3;
    const int nl   = lane & 31;
    const int nld  = min(n0 + nl, N - 1);

    const short8* gsrc = (const short8*)(g_lw + (size_t)ii * 131072);

    {
        short8 g[4];
#pragma unroll
        for (int i = 0; i < 4; ++i) g[i] = gsrc[tid + i * 256];
#pragma unroll
        for (int i = 0; i < 4; ++i) wb[tid + i * 256] = g[i];
        __syncthreads();
    }

    f32x16 acc[4] = {};
#pragma unroll
    for (int kt = 0; kt < 16; ++kt) {
        const float* srow = (kt < 8) ? (x + (size_t)nld * D + kt * 16 + half)
                                     : (hbuf + (size_t)nld * D + (kt - 8) * 16 + half);
        float4 u0 = *(const float4*)(srow);
        float4 u1 = *(const float4*)(srow + 4);
        short8 a;
        unsigned* ap = (unsigned*)&a;
        ap[0] = pk2(u0.x, u0.y); ap[1] = pk2(u0.z, u0.w);
        ap[2] = pk2(u1.x, u1.y); ap[3] = pk2(u1.z, u1.w);

        short8 g[4];
        if (kt + 1 < 16) {
            const short8* p = gsrc + (size_t)(kt + 1) * 1024;
#pragma unroll
            for (int i = 0; i < 4; ++i) g[i] = p[tid + i * 256];
        }
        const short8* buf = wb + (kt & 1) * 1024;
#pragma unroll
        for (int q = 0; q < 4; ++q) {
            short8 b = buf[(q * 4 + w) * 64 + lane];
            acc[q] = MFMA(a, b, acc[q]);
        }
        if (kt + 1 < 16) {
            short8* d = wb + ((kt + 1) & 1) * 1024;
#pragma unroll
            for (int i = 0; i < 4; ++i) d[tid + i * 256] = g[i];
        }
        __syncthreads();
    }

    const int col = (w << 5) + nl;
    const float bi = bih[col]       + bhh[col];
    const float bf = bih[128 + col] + bhh[128 + col];
    const float bg = bih[256 + col] + bhh[256 + col];
    const float bo = bih[384 + col] + bhh[384 + col];
#pragma unroll
    for (int reg = 0; reg < 16; ++reg) {
        const int nn = (reg & 3) + 8 * (reg >> 2) + 4 * (lane >> 5);
        const int n = n0 + nn;
        if (n < N) {
            const float gi = acc[0][reg] + bi;
            const float gf = acc[1][reg] + bf;
            const float gg = acc[2][reg] + bg;
            const float go = acc[3][reg] + bo;
            float* cp = cbuf + (size_t)n * D + col;
            const float c2 = sigm(gf) * (*cp) + sigm(gi) * tanhf(gg);
            const float h2 = sigm(go) * tanhf(c2);
            *cp = c2;
            hbuf[(size_t)n * D + col] = h2;
        }
    }
}

extern "C" void kernel_launch(void* const* d_in, const int* in_sizes, int n_in,
                              void* d_out, int out_size, void* d_ws, size_t ws_size,
                              hipStream_t stream) {
    const float* node_feat   = (const float*)d_in[0];
    const float* node_feat_c = (const float*)d_in[1];
    const int*   edge        = (const int*)d_in[2];
    const float* edge_feat   = (const float*)d_in[3];
    const float* dist_feat   = (const float*)d_in[4];
    const float* msg_w0 = (const float*)d_in[5];
    const float* msg_b0 = (const float*)d_in[6];
    const float* msg_w1 = (const float*)d_in[7];
    const float* msg_b1 = (const float*)d_in[8];
    const float* att_w0 = (const float*)d_in[9];
    const float* att_b0 = (const float*)d_in[10];
    const float* att_w1 = (const float*)d_in[11];
    const float* att_b1 = (const float*)d_in[12];
    const float* lstm_wih = (const float*)d_in[13];
    const float* lstm_whh = (const float*)d_in[14];
    const float* lstm_bih = (const float*)d_in[15];
    const float* lstm_bhh = (const float*)d_in[16];

    float* state     = (float*)d_out;
    float* state_c   = (float*)d_ws;
    float* state_msg = (float*)d_ws + (size_t)N * D;

    // sort edges by dst (per call; edge list static across layers)
    zero_cnt_kernel<<<256, 256, 0, stream>>>();
    hist_kernel<<<(M + 255) / 256, 256, 0, stream>>>(edge);
    scanA_kernel<<<NBLK, 256, 0, stream>>>();
    scanB_kernel<<<1, 256, 0, stream>>>();
    scanC_kernel<<<NBLK, 256, 0, stream>>>();
    scatter_kernel<<<(M + 255) / 256, 256, 0, stream>>>(edge);

    pack_efdf<<<25000, 256, 0, stream>>>(edge_feat, dist_feat);
    pack_edge<<<640, 256, 0, stream>>>(msg_w0, att_w0, msg_w1, att_w1);
    pack_lstm<<<1024, 256, 0, stream>>>(lstm_wih, lstm_whh);

    init_kernel<<<2048, 256, 0, stream>>>((const float4*)node_feat, (const float4*)node_feat_c,
                                          (float4*)state, (float4*)state_c);

    for (int ii = 0; ii < 2; ++ii) {
        prep_kernel<<<2048, 256, 0, stream>>>((float4*)state, (float4*)state_msg, ii > 0 ? 1 : 0);

        edge_mfma<<<M / TE, 256, 0, stream>>>(
            ii,
            msg_b0 + (size_t)ii * D, msg_b1 + (size_t)ii * D,
            att_b0 + (size_t)ii * D, att_b1 + (size_t)ii * D,
            state_msg);

        lstm_mfma<<<(N + 31) / 32, 256, 0, stream>>>(
            state_msg, state, state_c, ii,
            lstm_bih + (size_t)ii * 4 * D, lstm_bhh + (size_t)ii * 4 * D);
    }
}

// Round 7
// 914.711 us; speedup vs baseline: 6.2876x; 1.0182x over previous
//
#include <hip/hip_runtime.h>
#include <hip/hip_bf16.h>

constexpr int N  = 50000;
constexpr int M  = 800000;
constexpr int D  = 128;
constexpr int IN = 192;   // D + EF + DF
constexpr int TE = 128;   // edges per block (edge kernel)
constexpr int NCH = 20;   // 8KB weight chunks per layer
constexpr int NBLK = (N + 255) / 256;   // scan blocks

typedef __attribute__((ext_vector_type(4)))  short short4v;
typedef __attribute__((ext_vector_type(8)))  short short8;
typedef __attribute__((ext_vector_type(16))) float f32x16;

// packed bf16 edge weights: 2 layers x [W0m(3072 s8)|W1m(2048)|W0a(3072)|W1a(2048)]
__device__ __align__(16) short g_wp[163840];
// packed bf16 LSTM weights
__device__ __align__(16) short g_lw[262144];
// packed bf16 [ef|df] rows, in SORTED edge order: M x 64
__device__ __align__(16) short g_efdf[(size_t)M * 64];
// bf16 shadow of state (edge-input view), rewritten per layer
__device__ __align__(16) short g_sbf[(size_t)N * D];
// sort machinery
__device__ int g_cnt[N];       // histogram -> exclusive offsets -> scatter cursors
__device__ int g_part[NBLK];   // scan partials
__device__ int g_ssrc[M];      // src, sorted by dst
__device__ int g_sdst[M];      // dst, sorted
__device__ int g_inv[M];       // sorted position -> original edge

__device__ __forceinline__ float sigm(float x) { return 1.0f / (1.0f + __expf(-x)); }

__device__ __forceinline__ short f2bf(float f) {
    unsigned u = __builtin_bit_cast(unsigned, f);
    u = (u + 0x7FFFu + ((u >> 16) & 1u)) >> 16;   // RNE
    return (short)u;
}
__device__ __forceinline__ float bf2f(short s) {
    return __builtin_bit_cast(float, ((unsigned)(unsigned short)s) << 16);
}
// pack 2 f32 -> u32 of 2 bf16 (lo=a, hi=b) via v_cvt_pk_bf16_f32
__device__ __forceinline__ unsigned pk2(float a, float b) {
    __hip_bfloat162 h = __float22bfloat162_rn(float2{a, b});
    unsigned u;
    __builtin_memcpy(&u, &h, 4);
    return u;
}

// ---------------- sort-by-dst (counting sort, per call) ----------------
__global__ void zero_cnt_kernel() {
    for (int i = blockIdx.x * 256 + threadIdx.x; i < N; i += gridDim.x * 256) g_cnt[i] = 0;
}
__global__ void hist_kernel(const int* __restrict__ edge) {
    int e = blockIdx.x * 256 + threadIdx.x;
    if (e < M) atomicAdd(&g_cnt[edge[e * 2 + 1]], 1);
}
__global__ void scanA_kernel() {   // block sums
    __shared__ int red[256];
    const int t = threadIdx.x;
    const int idx = blockIdx.x * 256 + t;
    red[t] = (idx < N) ? g_cnt[idx] : 0;
    __syncthreads();
#pragma unroll
    for (int s = 128; s > 0; s >>= 1) {
        if (t < s) red[t] += red[t + s];
        __syncthreads();
    }
    if (t == 0) g_part[blockIdx.x] = red[0];
}
__global__ void scanB_kernel() {   // 1 block: exclusive scan of partials
    __shared__ int sh[256];
    const int t = threadIdx.x;
    int v = (t < NBLK) ? g_part[t] : 0;
    sh[t] = v;
    __syncthreads();
    int x = v;
    for (int s = 1; s < 256; s <<= 1) {
        int y = (t >= s) ? sh[t - s] : 0;
        __syncthreads();
        x += y; sh[t] = x;
        __syncthreads();
    }
    if (t < NBLK) g_part[t] = x - v;
}
__global__ void scanC_kernel() {   // per-block exclusive scan + base
    __shared__ int sh[256];
    const int t = threadIdx.x;
    const int idx = blockIdx.x * 256 + t;
    int v = (idx < N) ? g_cnt[idx] : 0;
    sh[t] = v;
    __syncthreads();
    int x = v;
    for (int s = 1; s < 256; s <<= 1) {
        int y = (t >= s) ? sh[t - s] : 0;
        __syncthreads();
        x += y; sh[t] = x;
        __syncthreads();
    }
    if (idx < N) g_cnt[idx] = g_part[blockIdx.x] + x - v;
}
__global__ void scatter_kernel(const int* __restrict__ edge) {
    int e = blockIdx.x * 256 + threadIdx.x;
    if (e < M) {
        const int s = edge[e * 2], d = edge[e * 2 + 1];
        const int p = atomicAdd(&g_cnt[d], 1);
        g_ssrc[p] = s;
        g_sdst[p] = d;
        g_inv[p]  = e;
    }
}

// ---------------- packs ----------------
__global__ void pack_edge(const float* __restrict__ w0m, const float* __restrict__ w0a,
                          const float* __restrict__ w1m, const float* __restrict__ w1a) {
    int gid = blockIdx.x * 256 + threadIdx.x;          // 0..163839
    int ii = gid / 81920;
    int r  = gid % 81920;
    int p  = r / 40960;  r %= 40960;
    int which = (r >= 24576) ? 1 : 0;
    int r2 = which ? r - 24576 : r;
    int e    = r2 & 7;
    int f    = r2 >> 3;
    int lane = f & 63;
    int ktct = f >> 6;
    int ct = ktct & 3, kt = ktct >> 2;
    int k   = kt * 16 + ((lane >> 5) << 3) + e;
    int col = ct * 32 + (lane & 31);
    const float* w0 = p ? w0a : w0m;
    const float* w1 = p ? w1a : w1m;
    float v = which ? w1[((size_t)ii * D + k) * D + col]
                    : w0[((size_t)ii * IN + k) * D + col];
    g_wp[gid] = f2bf(v);
}

__global__ void pack_lstm(const float* __restrict__ wih, const float* __restrict__ whh) {
    int gid = blockIdx.x * 256 + threadIdx.x;          // 0..262143
    int ii = gid >> 17;
    int r  = gid & 131071;
    int e = r & 7, f = r >> 3;
    int lane = f & 63, rest = f >> 6;
    int cf = rest & 15, kt = rest >> 4;
    int col = cf * 32 + (lane & 31);
    int k   = (kt & 7) * 16 + ((lane >> 5) << 3) + e;
    const float* src = (kt < 8) ? wih : whh;
    g_lw[gid] = f2bf(src[((size_t)ii * 512 + col) * D + k]);
}

// ef/df -> bf16, gathered via inverse perm, written CONTIGUOUS in sorted order
__global__ void pack_efdf(const float* __restrict__ ef, const float* __restrict__ df) {
    int gid = blockIdx.x * 256 + threadIdx.x;          // 0..6399999
    int p = gid >> 3, c0 = (gid & 7) * 8;
    const int e = g_inv[p];
    const float* s = (c0 < 32) ? (ef + (size_t)e * 32 + c0) : (df + (size_t)e * 32 + (c0 - 32));
    float4 u0 = *(const float4*)s, u1 = *(const float4*)(s + 4);
    short8 t;
    unsigned* tp = (unsigned*)&t;
    tp[0] = pk2(u0.x, u0.y); tp[1] = pk2(u0.z, u0.w);
    tp[2] = pk2(u1.x, u1.y); tp[3] = pk2(u1.z, u1.w);
    *(short8*)(g_efdf + (size_t)gid * 8) = t;
}

// ---------------- init / per-layer prep ----------------
__global__ void init_kernel(const float4* __restrict__ nf, const float4* __restrict__ nfc,
                            float4* __restrict__ state, float4* __restrict__ state_c) {
    const int total = N * D / 4;
    for (int i = blockIdx.x * blockDim.x + threadIdx.x; i < total; i += gridDim.x * blockDim.x) {
        state[i]   = nf[i];
        state_c[i] = nfc[i];
    }
}

__global__ void prep_kernel(float4* __restrict__ state, float4* __restrict__ msg, int do_relu) {
    const int total = N * D / 4;
    const float4 z = make_float4(0.f, 0.f, 0.f, 0.f);
    for (int i = blockIdx.x * blockDim.x + threadIdx.x; i < total; i += gridDim.x * blockDim.x) {
        float4 v = state[i];
        if (do_relu) {
            v.x = fmaxf(v.x, 0.f); v.y = fmaxf(v.y, 0.f);
            v.z = fmaxf(v.z, 0.f); v.w = fmaxf(v.w, 0.f);
            state[i] = v;
        }
        short4v b;
        unsigned* bp = (unsigned*)&b;
        bp[0] = pk2(v.x, v.y); bp[1] = pk2(v.z, v.w);
        *(short4v*)(g_sbf + (size_t)i * 4) = b;
        msg[i] = z;
    }
}

// ---------------- edge kernel: 8KB-chunk dbuf weight pipeline, 512 threads ----------------
#define MFMA(a, b, c) __builtin_amdgcn_mfma_f32_32x32x16_bf16(a, b, c, 0, 0, 0)

// 6 chunks (12 kt), A from registers
template<int BASE>
__device__ __forceinline__ void gemmA(const short8* __restrict__ gsrc, short8* wb,
                                      const short8 a1[12], int tid, int lane, int cg,
                                      f32x16& o0, f32x16& o1) {
    f32x16 acc0 = {}, acc1 = {};
#pragma unroll
    for (int c = 0; c < 6; ++c) {
        const int gc = BASE + c;
        short8 g;
        if (gc + 1 < NCH) g = gsrc[(size_t)(gc + 1) * 512 + tid];
        const short8* buf = wb + (gc & 1) * 512;
#pragma unroll
        for (int kl = 0; kl < 2; ++kl) {
            short8 b0 = buf[(kl * 4 + cg * 2 + 0) * 64 + lane];
            short8 b1 = buf[(kl * 4 + cg * 2 + 1) * 64 + lane];
            acc0 = MFMA(a1[c * 2 + kl], b0, acc0);
            acc1 = MFMA(a1[c * 2 + kl], b1, acc1);
        }
        if (gc + 1 < NCH) wb[((gc + 1) & 1) * 512 + tid] = g;
        __syncthreads();
    }
    o0 = acc0; o1 = acc1;
}

// 4 chunks (8 kt), A from hidden LDS
template<int BASE>
__device__ __forceinline__ void gemmH(const short8* __restrict__ gsrc, short8* wb,
                                      const short (*hsr)[136], int tid, int lane, int cg, int half,
                                      f32x16& o0, f32x16& o1) {
    f32x16 acc0 = {}, acc1 = {};
#pragma unroll
    for (int c = 0; c < 4; ++c) {
        const int gc = BASE + c;
        short8 g;
        if (gc + 1 < NCH) g = gsrc[(size_t)(gc + 1) * 512 + tid];
        const short8* buf = wb + (gc & 1) * 512;
#pragma unroll
        for (int kl = 0; kl < 2; ++kl) {
            const int kt = c * 2 + kl;
            short8 a2 = *(const short8*)&hsr[lane & 31][kt * 16 + half];
            short8 b0 = buf[(kl * 4 + cg * 2 + 0) * 64 + lane];
            short8 b1 = buf[(kl * 4 + cg * 2 + 1) * 64 + lane];
            acc0 = MFMA(a2, b0, acc0);
            acc1 = MFMA(a2, b1, acc1);
        }
        if (gc + 1 < NCH) wb[((gc + 1) & 1) * 512 + tid] = g;
        __syncthreads();
    }
    o0 = acc0; o1 = acc1;
}

__device__ __forceinline__ void hwrite(short (*hsr)[136], const f32x16& a0, const f32x16& a1v,
                                       const float* __restrict__ b0, int lane, int cg) {
#pragma unroll
    for (int ct = 0; ct < 2; ++ct) {
        const int col = cg * 64 + ct * 32 + (lane & 31);
        const float bv = b0[col];
        f32x16 a = ct ? a1v : a0;
#pragma unroll
        for (int rp = 0; rp < 8; ++rp) {
            const int reg = rp * 2;
            const int row = (reg & 3) + 8 * (reg >> 2) + 4 * (lane >> 5);
            const unsigned pr = pk2(fmaxf(a[reg] + bv, 0.f), fmaxf(a[reg + 1] + bv, 0.f));
            hsr[row][col]     = (short)(pr & 0xFFFF);
            hsr[row + 1][col] = (short)(pr >> 16);
        }
    }
}

__global__ __launch_bounds__(512, 4)
void edge_mfma(int ii,
               const float* __restrict__ b0m, const float* __restrict__ b1m,
               const float* __restrict__ b0a, const float* __restrict__ b1a,
               float* __restrict__ state_msg) {
    // pool: wb 16384 | hs 4x32x136x2 = 34816  -> 51200 ; sdst 512 at end = 51712 B
    // epilogue overlays [0, 33792) as f32 vt[64][132] (2 passes)
    __shared__ __align__(16) char pool[51712];
    short8* wb = (short8*)pool;
    short (*hs)[32][136] = (short(*)[32][136])(pool + 16384);
    int* sdst = (int*)(pool + 51200);

    const int tid  = threadIdx.x;
    const int lane = tid & 63;
    const int w    = tid >> 6;          // 0..7
    const int rt   = w >> 1;            // 0..3  (32-edge group)
    const int cg   = w & 1;             // 0..1  (64-col group)
    const int e0   = blockIdx.x * TE;

    if (tid < TE) sdst[tid] = g_sdst[e0 + tid];

    // ---- gather A1 fragments from bf16 shadow (sorted edge order)
    const int er   = e0 + rt * 32 + (lane & 31);
    const int half = (lane >> 5) << 3;
    const int s  = g_ssrc[er];
    const int d2 = g_sdst[er];
    const short* srow = g_sbf + (size_t)s  * D;
    const short* drow = g_sbf + (size_t)d2 * D;
    short8 a1[12];
#pragma unroll
    for (int kt = 0; kt < 8; ++kt) {
        const int k0 = kt * 16 + half;
        short8 sv = *(const short8*)(srow + k0);
        short8 dv = *(const short8*)(drow + k0);
        short8 t;
        unsigned* tp = (unsigned*)&t;
#pragma unroll
        for (int i = 0; i < 4; ++i)
            tp[i] = pk2(bf2f(sv[2 * i])     - bf2f(dv[2 * i]),
                        bf2f(sv[2 * i + 1]) - bf2f(dv[2 * i + 1]));
        a1[kt] = t;
    }
#pragma unroll
    for (int kt = 8; kt < 12; ++kt)
        a1[kt] = *(const short8*)(g_efdf + (size_t)er * 64 + (kt - 8) * 16 + half);

    const short8* gsrc = (const short8*)(g_wp + (size_t)ii * 81920);

    // prologue: stage chunk 0 (512 threads x 16B = 8KB)
    wb[tid] = gsrc[tid];
    __syncthreads();

    f32x16 t0, t1, m0, m1, c0, c1;
    gemmA<0>(gsrc, wb, a1, tid, lane, cg, t0, t1);            // msg GEMM1 (chunks 0-5)
    hwrite(hs[rt], t0, t1, b0m, lane, cg);
    __syncthreads();
    gemmH<6>(gsrc, wb, hs[rt], tid, lane, cg, half, m0, m1);  // msg GEMM2 (6-9)

    // pack (msg + bias) to bf16: frees 16 regs across the att path
    unsigned mb[16];
#pragma unroll
    for (int ct = 0; ct < 2; ++ct) {
        const float bm = b1m[cg * 64 + ct * 32 + (lane & 31)];
        f32x16 mv = ct ? m1 : m0;
#pragma unroll
        for (int rp = 0; rp < 8; ++rp)
            mb[ct * 8 + rp] = pk2(mv[rp * 2] + bm, mv[rp * 2 + 1] + bm);
    }

    gemmA<10>(gsrc, wb, a1, tid, lane, cg, t0, t1);           // att GEMM1 (10-15)
    hwrite(hs[rt], t0, t1, b0a, lane, cg);
    __syncthreads();
    gemmH<16>(gsrc, wb, hs[rt], tid, lane, cg, half, c0, c1); // att GEMM2 (16-19)

    // ---- 2-pass combine (f32 vt overlay) + segmented reduction over sorted runs
    float (*vt)[132] = (float(*)[132])pool;
    const int colr = tid & 127;
    const int sub  = tid >> 7;          // 0..3
#pragma unroll
    for (int pass = 0; pass < 2; ++pass) {
        if ((rt >> 1) == pass) {
#pragma unroll
            for (int ct = 0; ct < 2; ++ct) {
                const int col = cg * 64 + ct * 32 + (lane & 31);
                const float ba = b1a[col];
                f32x16 av = ct ? c1 : c0;
#pragma unroll
                for (int rp = 0; rp < 8; ++rp) {
                    const int reg = rp * 2;
                    const unsigned u = mb[ct * 8 + rp];
                    const int row = (rt & 1) * 32 + (reg & 3) + 8 * (reg >> 2) + 4 * (lane >> 5);
                    vt[row][col]     = bf2f((short)(u & 0xFFFF)) * sigm(av[reg] + ba);
                    vt[row + 1][col] = bf2f((short)(u >> 16))    * sigm(av[reg + 1] + ba);
                }
            }
        }
        __syncthreads();
        const int gbase = pass * 64 + sub * 16;
        float run = 0.f;
        int cur = sdst[gbase];
#pragma unroll 4
        for (int r = 0; r < 16; ++r) {
            const int dd = sdst[gbase + r];
            if (dd != cur) {
                atomicAdd(state_msg + (size_t)cur * D + colr, run);
                run = 0.f; cur = dd;
            }
            run += vt[sub * 16 + r][colr];
        }
        atomicAdd(state_msg + (size_t)cur * D + colr, run);
        __syncthreads();
    }
}

// ---------------- LSTM: bf16 MFMA (unchanged) ----------------
__global__ __launch_bounds__(256, 4)
void lstm_mfma(const float* __restrict__ x, float* __restrict__ hbuf, float* __restrict__ cbuf,
               int ii,
               const float* __restrict__ bih, const float* __restrict__ bhh) {
    __shared__ short8 wb[2048];
    const int tid  = threadIdx.x;
    const int lane = tid & 63;
    const int w    = tid >> 6;
    const int n0   = blockIdx.x * 32;
    const int half = (lane >> 5) << 3;
    const int nl   = lane & 31;
    const int nld  = min(n0 + nl, N - 1);

    const short8* gsrc = (const short8*)(g_lw + (size_t)ii * 131072);

    {
        short8 g[4];
#pragma unroll
        for (int i = 0; i < 4; ++i) g[i] = gsrc[tid + i * 256];
#pragma unroll
        for (int i = 0; i < 4; ++i) wb[tid + i * 256] = g[i];
        __syncthreads();
    }

    f32x16 acc[4] = {};
#pragma unroll
    for (int kt = 0; kt < 16; ++kt) {
        const float* srow = (kt < 8) ? (x + (size_t)nld * D + kt * 16 + half)
                                     : (hbuf + (size_t)nld * D + (kt - 8) * 16 + half);
        float4 u0 = *(const float4*)(srow);
        float4 u1 = *(const float4*)(srow + 4);
        short8 a;
        unsigned* ap = (unsigned*)&a;
        ap[0] = pk2(u0.x, u0.y); ap[1] = pk2(u0.z, u0.w);
        ap[2] = pk2(u1.x, u1.y); ap[3] = pk2(u1.z, u1.w);

        short8 g[4];
        if (kt + 1 < 16) {
            const short8* p = gsrc + (size_t)(kt + 1) * 1024;
#pragma unroll
            for (int i = 0; i < 4; ++i) g[i] = p[tid + i * 256];
        }
        const short8* buf = wb + (kt & 1) * 1024;
#pragma unroll
        for (int q = 0; q < 4; ++q) {
            short8 b = buf[(q * 4 + w) * 64 + lane];
            acc[q] = MFMA(a, b, acc[q]);
        }
        if (kt + 1 < 16) {
            short8* d = wb + ((kt + 1) & 1) * 1024;
#pragma unroll
            for (int i = 0; i < 4; ++i) d[tid + i * 256] = g[i];
        }
        __syncthreads();
    }

    const int col = (w << 5) + nl;
    const float bi = bih[col]       + bhh[col];
    const float bf = bih[128 + col] + bhh[128 + col];
    const float bg = bih[256 + col] + bhh[256 + col];
    const float bo = bih[384 + col] + bhh[384 + col];
#pragma unroll
    for (int reg = 0; reg < 16; ++reg) {
        const int nn = (reg & 3) + 8 * (reg >> 2) + 4 * (lane >> 5);
        const int n = n0 + nn;
        if (n < N) {
            const float gi = acc[0][reg] + bi;
            const float gf = acc[1][reg] + bf;
            const float gg = acc[2][reg] + bg;
            const float go = acc[3][reg] + bo;
            float* cp = cbuf + (size_t)n * D + col;
            const float c2 = sigm(gf) * (*cp) + sigm(gi) * tanhf(gg);
            const float h2 = sigm(go) * tanhf(c2);
            *cp = c2;
            hbuf[(size_t)n * D + col] = h2;
        }
    }
}

extern "C" void kernel_launch(void* const* d_in, const int* in_sizes, int n_in,
                              void* d_out, int out_size, void* d_ws, size_t ws_size,
                              hipStream_t stream) {
    const float* node_feat   = (const float*)d_in[0];
    const float* node_feat_c = (const float*)d_in[1];
    const int*   edge        = (const int*)d_in[2];
    const float* edge_feat   = (const float*)d_in[3];
    const float* dist_feat   = (const float*)d_in[4];
    const float* msg_w0 = (const float*)d_in[5];
    const float* msg_b0 = (const float*)d_in[6];
    const float* msg_w1 = (const float*)d_in[7];
    const float* msg_b1 = (const float*)d_in[8];
    const float* att_w0 = (const float*)d_in[9];
    const float* att_b0 = (const float*)d_in[10];
    const float* att_w1 = (const float*)d_in[11];
    const float* att_b1 = (const float*)d_in[12];
    const float* lstm_wih = (const float*)d_in[13];
    const float* lstm_whh = (const float*)d_in[14];
    const float* lstm_bih = (const float*)d_in[15];
    const float* lstm_bhh = (const float*)d_in[16];

    float* state     = (float*)d_out;
    float* state_c   = (float*)d_ws;
    float* state_msg = (float*)d_ws + (size_t)N * D;

    // sort edges by dst (per call; edge list static across layers)
    zero_cnt_kernel<<<256, 256, 0, stream>>>();
    hist_kernel<<<(M + 255) / 256, 256, 0, stream>>>(edge);
    scanA_kernel<<<NBLK, 256, 0, stream>>>();
    scanB_kernel<<<1, 256, 0, stream>>>();
    scanC_kernel<<<NBLK, 256, 0, stream>>>();
    scatter_kernel<<<(M + 255) / 256, 256, 0, stream>>>(edge);

    pack_efdf<<<25000, 256, 0, stream>>>(edge_feat, dist_feat);
    pack_edge<<<640, 256, 0, stream>>>(msg_w0, att_w0, msg_w1, att_w1);
    pack_lstm<<<1024, 256, 0, stream>>>(lstm_wih, lstm_whh);

    init_kernel<<<2048, 256, 0, stream>>>((const float4*)node_feat, (const float4*)node_feat_c,
                                          (float4*)state, (float4*)state_c);

    for (int ii = 0; ii < 2; ++ii) {
        prep_kernel<<<2048, 256, 0, stream>>>((float4*)state, (float4*)state_msg, ii > 0 ? 1 : 0);

        edge_mfma<<<M / TE, 512, 0, stream>>>(
            ii,
            msg_b0 + (size_t)ii * D, msg_b1 + (size_t)ii * D,
            att_b0 + (size_t)ii * D, att_b1 + (size_t)ii * D,
            state_msg);

        lstm_mfma<<<(N + 31) / 32, 256, 0, stream>>>(
            state_msg, state, state_c, ii,
            lstm_bih + (size_t)ii * 4 * D, lstm_bhh + (size_t)ii * 4 * D);
    }
}

// Round 9
// 887.802 us; speedup vs baseline: 6.4782x; 1.0303x over previous
//
#include <hip/hip_runtime.h>
#include <hip/hip_bf16.h>

constexpr int N  = 50000;
constexpr int M  = 800000;
constexpr int D  = 128;
constexpr int IN = 192;   // D + EF + DF
constexpr int TE = 128;   // edges per block (edge kernel)
constexpr int NCH = 10;   // 16KB weight chunks per layer
constexpr int NBLK = (N + 255) / 256;   // scan blocks

typedef __attribute__((ext_vector_type(4)))  short short4v;
typedef __attribute__((ext_vector_type(8)))  short short8;
typedef __attribute__((ext_vector_type(16))) float f32x16;
typedef _Float16 half8  __attribute__((ext_vector_type(8)));

// packed fp16 edge weights: 2 layers x [W0m(3072 s8)|W1m(2048)|W0a(3072)|W1a(2048)]
__device__ __align__(16) short g_wp[163840];
// packed bf16 LSTM weights
__device__ __align__(16) short g_lw[262144];
// packed fp16 [ef|df] rows, in SORTED edge order: M x 64
__device__ __align__(16) short g_efdf[(size_t)M * 64];
// fp16 shadow of state (edge-input view), rewritten per layer
__device__ __align__(16) short g_sbf[(size_t)N * D];
// sort machinery
__device__ int g_cnt[N];       // histogram -> exclusive offsets -> scatter cursors
__device__ int g_part[NBLK];   // scan partials
__device__ int g_ssrc[M];      // src, sorted by dst
__device__ int g_sdst[M];      // dst, sorted
__device__ int g_inv[M];       // sorted position -> original edge

__device__ __forceinline__ float sigm(float x) { return 1.0f / (1.0f + __expf(-x)); }

__device__ __forceinline__ short f2bf(float f) {
    unsigned u = __builtin_bit_cast(unsigned, f);
    u = (u + 0x7FFFu + ((u >> 16) & 1u)) >> 16;   // RNE
    return (short)u;
}
// bf16 pair pack (LSTM path)
__device__ __forceinline__ unsigned pk2(float a, float b) {
    __hip_bfloat162 h = __float22bfloat162_rn(float2{a, b});
    unsigned u;
    __builtin_memcpy(&u, &h, 4);
    return u;
}
// fp16 pair pack: v_cvt_pkrtz_f16_f32 (1 op)
__device__ __forceinline__ unsigned pkh(float a, float b) {
    auto h = __builtin_amdgcn_cvt_pkrtz(a, b);
    unsigned u;
    __builtin_memcpy(&u, &h, 4);
    return u;
}
__device__ __forceinline__ short f2h(float f) {
    _Float16 h = (_Float16)f;
    return __builtin_bit_cast(short, h);
}
__device__ __forceinline__ float h2f(short s) {
    _Float16 h = __builtin_bit_cast(_Float16, s);
    return (float)h;
}

// ---------------- sort-by-dst (counting sort, per call) ----------------
__global__ void zero_cnt_kernel() {
    for (int i = blockIdx.x * 256 + threadIdx.x; i < N; i += gridDim.x * 256) g_cnt[i] = 0;
}
__global__ void hist_kernel(const int* __restrict__ edge) {
    int e = blockIdx.x * 256 + threadIdx.x;
    if (e < M) atomicAdd(&g_cnt[edge[e * 2 + 1]], 1);
}
__global__ void scanA_kernel() {   // block sums
    __shared__ int red[256];
    const int t = threadIdx.x;
    const int idx = blockIdx.x * 256 + t;
    red[t] = (idx < N) ? g_cnt[idx] : 0;
    __syncthreads();
#pragma unroll
    for (int s = 128; s > 0; s >>= 1) {
        if (t < s) red[t] += red[t + s];
        __syncthreads();
    }
    if (t == 0) g_part[blockIdx.x] = red[0];
}
__global__ void scanB_kernel() {   // 1 block: exclusive scan of partials
    __shared__ int sh[256];
    const int t = threadIdx.x;
    int v = (t < NBLK) ? g_part[t] : 0;
    sh[t] = v;
    __syncthreads();
    int x = v;
    for (int s = 1; s < 256; s <<= 1) {
        int y = (t >= s) ? sh[t - s] : 0;
        __syncthreads();
        x += y; sh[t] = x;
        __syncthreads();
    }
    if (t < NBLK) g_part[t] = x - v;
}
__global__ void scanC_kernel() {   // per-block exclusive scan + base
    __shared__ int sh[256];
    const int t = threadIdx.x;
    const int idx = blockIdx.x * 256 + t;
    int v = (idx < N) ? g_cnt[idx] : 0;
    sh[t] = v;
    __syncthreads();
    int x = v;
    for (int s = 1; s < 256; s <<= 1) {
        int y = (t >= s) ? sh[t - s] : 0;
        __syncthreads();
        x += y; sh[t] = x;
        __syncthreads();
    }
    if (idx < N) g_cnt[idx] = g_part[blockIdx.x] + x - v;
}
__global__ void scatter_kernel(const int* __restrict__ edge) {
    int e = blockIdx.x * 256 + threadIdx.x;
    if (e < M) {
        const int s = edge[e * 2], d = edge[e * 2 + 1];
        const int p = atomicAdd(&g_cnt[d], 1);
        g_ssrc[p] = s;
        g_sdst[p] = d;
        g_inv[p]  = e;
    }
}

// ---------------- packs ----------------
__global__ void pack_edge(const float* __restrict__ w0m, const float* __restrict__ w0a,
                          const float* __restrict__ w1m, const float* __restrict__ w1a) {
    int gid = blockIdx.x * 256 + threadIdx.x;          // 0..163839
    int ii = gid / 81920;
    int r  = gid % 81920;
    int p  = r / 40960;  r %= 40960;
    int which = (r >= 24576) ? 1 : 0;
    int r2 = which ? r - 24576 : r;
    int e    = r2 & 7;
    int f    = r2 >> 3;
    int lane = f & 63;
    int ktct = f >> 6;
    int ct = ktct & 3, kt = ktct >> 2;
    int k   = kt * 16 + ((lane >> 5) << 3) + e;
    int col = ct * 32 + (lane & 31);
    const float* w0 = p ? w0a : w0m;
    const float* w1 = p ? w1a : w1m;
    float v = which ? w1[((size_t)ii * D + k) * D + col]
                    : w0[((size_t)ii * IN + k) * D + col];
    g_wp[gid] = f2h(v);
}

__global__ void pack_lstm(const float* __restrict__ wih, const float* __restrict__ whh) {
    int gid = blockIdx.x * 256 + threadIdx.x;          // 0..262143
    int ii = gid >> 17;
    int r  = gid & 131071;
    int e = r & 7, f = r >> 3;
    int lane = f & 63, rest = f >> 6;
    int cf = rest & 15, kt = rest >> 4;
    int col = cf * 32 + (lane & 31);
    int k   = (kt & 7) * 16 + ((lane >> 5) << 3) + e;
    const float* src = (kt < 8) ? wih : whh;
    g_lw[gid] = f2bf(src[((size_t)ii * 512 + col) * D + k]);
}

// ef/df -> fp16, gathered via inverse perm, written CONTIGUOUS in sorted order
__global__ void pack_efdf(const float* __restrict__ ef, const float* __restrict__ df) {
    int gid = blockIdx.x * 256 + threadIdx.x;          // 0..6399999
    int p = gid >> 3, c0 = (gid & 7) * 8;
    const int e = g_inv[p];
    const float* s = (c0 < 32) ? (ef + (size_t)e * 32 + c0) : (df + (size_t)e * 32 + (c0 - 32));
    float4 u0 = *(const float4*)s, u1 = *(const float4*)(s + 4);
    short8 t;
    unsigned* tp = (unsigned*)&t;
    tp[0] = pkh(u0.x, u0.y); tp[1] = pkh(u0.z, u0.w);
    tp[2] = pkh(u1.x, u1.y); tp[3] = pkh(u1.z, u1.w);
    *(short8*)(g_efdf + (size_t)gid * 8) = t;
}

// ---------------- init / per-layer prep ----------------
__global__ void init_kernel(const float4* __restrict__ nf, const float4* __restrict__ nfc,
                            float4* __restrict__ state, float4* __restrict__ state_c) {
    const int total = N * D / 4;
    for (int i = blockIdx.x * blockDim.x + threadIdx.x; i < total; i += gridDim.x * blockDim.x) {
        state[i]   = nf[i];
        state_c[i] = nfc[i];
    }
}

__global__ void prep_kernel(float4* __restrict__ state, float4* __restrict__ msg, int do_relu) {
    const int total = N * D / 4;
    const float4 z = make_float4(0.f, 0.f, 0.f, 0.f);
    for (int i = blockIdx.x * blockDim.x + threadIdx.x; i < total; i += gridDim.x * blockDim.x) {
        float4 v = state[i];
        if (do_relu) {
            v.x = fmaxf(v.x, 0.f); v.y = fmaxf(v.y, 0.f);
            v.z = fmaxf(v.z, 0.f); v.w = fmaxf(v.w, 0.f);
            state[i] = v;
        }
        short4v b;
        unsigned* bp = (unsigned*)&b;
        bp[0] = pkh(v.x, v.y); bp[1] = pkh(v.z, v.w);
        *(short4v*)(g_sbf + (size_t)i * 4) = b;
        msg[i] = z;
    }
}

// ---------------- edge kernel: 16KB-chunk dbuf fp16 weight pipeline, 512 threads ----------------
#define MFMA16(a, b, c) __builtin_amdgcn_mfma_f32_32x32x16_f16(a, b, c, 0, 0, 0)
#define MFMABF(a, b, c) __builtin_amdgcn_mfma_f32_32x32x16_bf16(a, b, c, 0, 0, 0)

// chunk = 1024 short8 (16 KB) = 4 kt. GEMM1: 3 chunks. GEMM2: 2 chunks.
template<int BASE, int NC>
__device__ __forceinline__ void gemmA(const short8* __restrict__ gsrc, short8* wb,
                                      const half8 a1[12], int tid, int lane, int cg,
                                      f32x16& o0, f32x16& o1) {
    f32x16 acc0 = {}, acc1 = {};
#pragma unroll
    for (int c = 0; c < NC; ++c) {
        const int gc = BASE + c;
        short8 g0, g1;
        if (gc + 1 < NCH) {
            g0 = gsrc[(size_t)(gc + 1) * 1024 + tid];
            g1 = gsrc[(size_t)(gc + 1) * 1024 + tid + 512];
        }
        const short8* buf = wb + (gc & 1) * 1024;
#pragma unroll
        for (int kl = 0; kl < 4; ++kl) {
            half8 b0 = __builtin_bit_cast(half8, buf[(kl * 4 + cg * 2 + 0) * 64 + lane]);
            half8 b1 = __builtin_bit_cast(half8, buf[(kl * 4 + cg * 2 + 1) * 64 + lane]);
            acc0 = MFMA16(a1[c * 4 + kl], b0, acc0);
            acc1 = MFMA16(a1[c * 4 + kl], b1, acc1);
        }
        if (gc + 1 < NCH) {
            short8* d = wb + ((gc + 1) & 1) * 1024;
            d[tid] = g0; d[tid + 512] = g1;
        }
        __syncthreads();
    }
    o0 = acc0; o1 = acc1;
}

template<int BASE, int NC>
__device__ __forceinline__ void gemmH(const short8* __restrict__ gsrc, short8* wb,
                                      const short (*hsr)[136], int tid, int lane, int cg, int half,
                                      f32x16& o0, f32x16& o1) {
    f32x16 acc0 = {}, acc1 = {};
#pragma unroll
    for (int c = 0; c < NC; ++c) {
        const int gc = BASE + c;
        short8 g0, g1;
        if (gc + 1 < NCH) {
            g0 = gsrc[(size_t)(gc + 1) * 1024 + tid];
            g1 = gsrc[(size_t)(gc + 1) * 1024 + tid + 512];
        }
        const short8* buf = wb + (gc & 1) * 1024;
#pragma unroll
        for (int kl = 0; kl < 4; ++kl) {
            const int kt = c * 4 + kl;
            half8 a2 = __builtin_bit_cast(half8, *(const short8*)&hsr[lane & 31][kt * 16 + half]);
            half8 b0 = __builtin_bit_cast(half8, buf[(kl * 4 + cg * 2 + 0) * 64 + lane]);
            half8 b1 = __builtin_bit_cast(half8, buf[(kl * 4 + cg * 2 + 1) * 64 + lane]);
            acc0 = MFMA16(a2, b0, acc0);
            acc1 = MFMA16(a2, b1, acc1);
        }
        if (gc + 1 < NCH) {
            short8* d = wb + ((gc + 1) & 1) * 1024;
            d[tid] = g0; d[tid + 512] = g1;
        }
        __syncthreads();
    }
    o0 = acc0; o1 = acc1;
}

__device__ __forceinline__ void hwrite(short (*hsr)[136], const f32x16& a0, const f32x16& a1v,
                                       const float* __restrict__ b0, int lane, int cg) {
#pragma unroll
    for (int ct = 0; ct < 2; ++ct) {
        const int col = cg * 64 + ct * 32 + (lane & 31);
        const float bv = b0[col];
        f32x16 a = ct ? a1v : a0;
#pragma unroll
        for (int rp = 0; rp < 8; ++rp) {
            const int reg = rp * 2;
            const int row = (reg & 3) + 8 * (reg >> 2) + 4 * (lane >> 5);
            const unsigned pr = pkh(fmaxf(a[reg] + bv, 0.f), fmaxf(a[reg + 1] + bv, 0.f));
            hsr[row][col]     = (short)(pr & 0xFFFF);
            hsr[row + 1][col] = (short)(pr >> 16);
        }
    }
}

__global__ __launch_bounds__(512, 4)
void edge_mfma(int ii,
               const float* __restrict__ b0m, const float* __restrict__ b1m,
               const float* __restrict__ b0a, const float* __restrict__ b1a,
               float* __restrict__ state_msg) {
    // pool: wb 32768 | hs 4x32x136x2 = 34816 | sdst 512  = 68096 B (2 blocks/CU)
    // epilogue overlays [0, 33792) as f32 vt[64][132] (2 passes); hs dead by then
    __shared__ __align__(16) char pool[68096];
    short8* wb = (short8*)pool;
    short (*hs)[32][136] = (short(*)[32][136])(pool + 32768);
    int* sdst = (int*)(pool + 67584);

    const int tid  = threadIdx.x;
    const int lane = tid & 63;
    const int w    = tid >> 6;          // 0..7
    const int rt   = w >> 1;            // 0..3  (32-edge group)
    const int cg   = w & 1;             // 0..1  (64-col group)
    const int e0   = blockIdx.x * TE;

    if (tid < TE) sdst[tid] = g_sdst[e0 + tid];

    // ---- gather A1 fragments from fp16 shadow (sorted edge order)
    const int er   = e0 + rt * 32 + (lane & 31);
    const int half = (lane >> 5) << 3;
    const int s  = g_ssrc[er];
    const int d2 = g_sdst[er];
    const short* srow = g_sbf + (size_t)s  * D;
    const short* drow = g_sbf + (size_t)d2 * D;
    half8 a1[12];
#pragma unroll
    for (int kt = 0; kt < 8; ++kt) {
        const int k0 = kt * 16 + half;
        half8 sv = __builtin_bit_cast(half8, *(const short8*)(srow + k0));
        half8 dv = __builtin_bit_cast(half8, *(const short8*)(drow + k0));
        a1[kt] = sv - dv;                      // 4x v_pk_add_f16
    }
#pragma unroll
    for (int kt = 8; kt < 12; ++kt)
        a1[kt] = __builtin_bit_cast(half8, *(const short8*)(g_efdf + (size_t)er * 64 + (kt - 8) * 16 + half));

    const short8* gsrc = (const short8*)(g_wp + (size_t)ii * 81920);

    // prologue: stage chunk 0 (512 threads x 32B = 16KB)
    wb[tid] = gsrc[tid];
    wb[tid + 512] = gsrc[tid + 512];
    __syncthreads();

    f32x16 t0, t1, m0, m1, c0, c1;
    gemmA<0, 3>(gsrc, wb, a1, tid, lane, cg, t0, t1);            // msg GEMM1 (chunks 0-2)
    hwrite(hs[rt], t0, t1, b0m, lane, cg);
    __syncthreads();
    gemmH<3, 2>(gsrc, wb, hs[rt], tid, lane, cg, half, m0, m1);  // msg GEMM2 (3-4)

    // pack (msg + bias) to fp16 pairs: frees 16 regs across the att path
    unsigned mb[16];
#pragma unroll
    for (int ct = 0; ct < 2; ++ct) {
        const float bm = b1m[cg * 64 + ct * 32 + (lane & 31)];
        f32x16 mv = ct ? m1 : m0;
#pragma unroll
        for (int rp = 0; rp < 8; ++rp)
            mb[ct * 8 + rp] = pkh(mv[rp * 2] + bm, mv[rp * 2 + 1] + bm);
    }

    gemmA<5, 3>(gsrc, wb, a1, tid, lane, cg, t0, t1);            // att GEMM1 (5-7)
    hwrite(hs[rt], t0, t1, b0a, lane, cg);
    __syncthreads();
    gemmH<8, 2>(gsrc, wb, hs[rt], tid, lane, cg, half, c0, c1);  // att GEMM2 (8-9)

    // ---- 2-pass combine (f32 vt overlay) + segmented reduction over sorted runs
    float (*vt)[132] = (float(*)[132])pool;
    const int colr = tid & 127;
    const int sub  = tid >> 7;          // 0..3
#pragma unroll
    for (int pass = 0; pass < 2; ++pass) {
        if ((rt >> 1) == pass) {
#pragma unroll
            for (int ct = 0; ct < 2; ++ct) {
                const int col = cg * 64 + ct * 32 + (lane & 31);
                const float ba = b1a[col];
                f32x16 av = ct ? c1 : c0;
#pragma unroll
                for (int rp = 0; rp < 8; ++rp) {
                    const int reg = rp * 2;
                    const unsigned u = mb[ct * 8 + rp];
                    const int row = (rt & 1) * 32 + (reg & 3) + 8 * (reg >> 2) + 4 * (lane >> 5);
                    vt[row][col]     = h2f((short)(u & 0xFFFF)) * sigm(av[reg] + ba);
                    vt[row + 1][col] = h2f((short)(u >> 16))    * sigm(av[reg + 1] + ba);
                }
            }
        }
        __syncthreads();
        const int gbase = pass * 64 + sub * 16;
        float run = 0.f;
        int cur = sdst[gbase];
#pragma unroll 4
        for (int r = 0; r < 16; ++r) {
            const int dd = sdst[gbase + r];
            if (dd != cur) {
                atomicAdd(state_msg + (size_t)cur * D + colr, run);
                run = 0.f; cur = dd;
            }
            run += vt[sub * 16 + r][colr];
        }
        atomicAdd(state_msg + (size_t)cur * D + colr, run);
        __syncthreads();
    }
}

// ---------------- LSTM: bf16 MFMA (unchanged) ----------------
__global__ __launch_bounds__(256, 4)
void lstm_mfma(const float* __restrict__ x, float* __restrict__ hbuf, float* __restrict__ cbuf,
               int ii,
               const float* __restrict__ bih, const float* __restrict__ bhh) {
    __shared__ short8 wb[2048];
    const int tid  = threadIdx.x;
    const int lane = tid & 63;
    const int w    = tid >> 6;
    const int n0   = blockIdx.x * 32;
    const int half = (lane >> 5) << 3;
    const int nl   = lane & 31;
    const int nld  = min(n0 + nl, N - 1);

    const short8* gsrc = (const short8*)(g_lw + (size_t)ii * 131072);

    {
        short8 g[4];
#pragma unroll
        for (int i = 0; i < 4; ++i) g[i] = gsrc[tid + i * 256];
#pragma unroll
        for (int i = 0; i < 4; ++i) wb[tid + i * 256] = g[i];
        __syncthreads();
    }

    f32x16 acc[4] = {};
#pragma unroll
    for (int kt = 0; kt < 16; ++kt) {
        const float* srow = (kt < 8) ? (x + (size_t)nld * D + kt * 16 + half)
                                     : (hbuf + (size_t)nld * D + (kt - 8) * 16 + half);
        float4 u0 = *(const float4*)(srow);
        float4 u1 = *(const float4*)(srow + 4);
        short8 a;
        unsigned* ap = (unsigned*)&a;
        ap[0] = pk2(u0.x, u0.y); ap[1] = pk2(u0.z, u0.w);
        ap[2] = pk2(u1.x, u1.y); ap[3] = pk2(u1.z, u1.w);

        short8 g[4];
        if (kt + 1 < 16) {
            const short8* p = gsrc + (size_t)(kt + 1) * 1024;
#pragma unroll
            for (int i = 0; i < 4; ++i) g[i] = p[tid + i * 256];
        }
        const short8* buf = wb + (kt & 1) * 1024;
#pragma unroll
        for (int q = 0; q < 4; ++q) {
            short8 b = buf[(q * 4 + w) * 64 + lane];
            acc[q] = MFMABF(a, b, acc[q]);
        }
        if (kt + 1 < 16) {
            short8* d = wb + ((kt + 1) & 1) * 1024;
#pragma unroll
            for (int i = 0; i < 4; ++i) d[tid + i * 256] = g[i];
        }
        __syncthreads();
    }

    const int col = (w << 5) + nl;
    const float bi = bih[col]       + bhh[col];
    const float bf = bih[128 + col] + bhh[128 + col];
    const float bg = bih[256 + col] + bhh[256 + col];
    const float bo = bih[384 + col] + bhh[384 + col];
#pragma unroll
    for (int reg = 0; reg < 16; ++reg) {
        const int nn = (reg & 3) + 8 * (reg >> 2) + 4 * (lane >> 5);
        const int n = n0 + nn;
        if (n < N) {
            const float gi = acc[0][reg] + bi;
            const float gf = acc[1][reg] + bf;
            const float gg = acc[2][reg] + bg;
            const float go = acc[3][reg] + bo;
            float* cp = cbuf + (size_t)n * D + col;
            const float c2 = sigm(gf) * (*cp) + sigm(gi) * tanhf(gg);
            const float h2 = sigm(go) * tanhf(c2);
            *cp = c2;
            hbuf[(size_t)n * D + col] = h2;
        }
    }
}

extern "C" void kernel_launch(void* const* d_in, const int* in_sizes, int n_in,
                              void* d_out, int out_size, void* d_ws, size_t ws_size,
                              hipStream_t stream) {
    const float* node_feat   = (const float*)d_in[0];
    const float* node_feat_c = (const float*)d_in[1];
    const int*   edge        = (const int*)d_in[2];
    const float* edge_feat   = (const float*)d_in[3];
    const float* dist_feat   = (const float*)d_in[4];
    const float* msg_w0 = (const float*)d_in[5];
    const float* msg_b0 = (const float*)d_in[6];
    const float* msg_w1 = (const float*)d_in[7];
    const float* msg_b1 = (const float*)d_in[8];
    const float* att_w0 = (const float*)d_in[9];
    const float* att_b0 = (const float*)d_in[10];
    const float* att_w1 = (const float*)d_in[11];
    const float* att_b1 = (const float*)d_in[12];
    const float* lstm_wih = (const float*)d_in[13];
    const float* lstm_whh = (const float*)d_in[14];
    const float* lstm_bih = (const float*)d_in[15];
    const float* lstm_bhh = (const float*)d_in[16];

    float* state     = (float*)d_out;
    float* state_c   = (float*)d_ws;
    float* state_msg = (float*)d_ws + (size_t)N * D;

    // sort edges by dst (per call; edge list static across layers)
    zero_cnt_kernel<<<256, 256, 0, stream>>>();
    hist_kernel<<<(M + 255) / 256, 256, 0, stream>>>(edge);
    scanA_kernel<<<NBLK, 256, 0, stream>>>();
    scanB_kernel<<<1, 256, 0, stream>>>();
    scanC_kernel<<<NBLK, 256, 0, stream>>>();
    scatter_kernel<<<(M + 255) / 256, 256, 0, stream>>>(edge);

    pack_efdf<<<25000, 256, 0, stream>>>(edge_feat, dist_feat);
    pack_edge<<<640, 256, 0, stream>>>(msg_w0, att_w0, msg_w1, att_w1);
    pack_lstm<<<1024, 256, 0, stream>>>(lstm_wih, lstm_whh);

    init_kernel<<<2048, 256, 0, stream>>>((const float4*)node_feat, (const float4*)node_feat_c,
                                          (float4*)state, (float4*)state_c);

    for (int ii = 0; ii < 2; ++ii) {
        prep_kernel<<<2048, 256, 0, stream>>>((float4*)state, (float4*)state_msg, ii > 0 ? 1 : 0);

        edge_mfma<<<M / TE, 512, 0, stream>>>(
            ii,
            msg_b0 + (size_t)ii * D, msg_b1 + (size_t)ii * D,
            att_b0 + (size_t)ii * D, att_b1 + (size_t)ii * D,
            state_msg);

        lstm_mfma<<<(N + 31) / 32, 256, 0, stream>>>(
            state_msg, state, state_c, ii,
            lstm_bih + (size_t)ii * 4 * D, lstm_bhh + (size_t)ii * 4 * D);
    }
}

// Round 10
// 858.220 us; speedup vs baseline: 6.7015x; 1.0345x over previous
//
#include <hip/hip_runtime.h>
#include <hip/hip_bf16.h>

constexpr int N  = 50000;
constexpr int M  = 800000;
constexpr int D  = 128;
constexpr int IN = 192;   // D + EF + DF
constexpr int TE = 128;   // edges per block (edge kernel)
constexpr int NCH = 10;   // 16KB weight chunks per layer
constexpr int NBLK = (N + 255) / 256;   // scan blocks

typedef __attribute__((ext_vector_type(4)))  short short4v;
typedef __attribute__((ext_vector_type(8)))  short short8;
typedef __attribute__((ext_vector_type(16))) float f32x16;
typedef _Float16 half8  __attribute__((ext_vector_type(8)));

// packed fp16 edge weights: 2 layers x [W0m(3072 s8)|W1m(2048)|W0a(3072)|W1a(2048)]
__device__ __align__(16) short g_wp[163840];
// packed bf16 LSTM weights
__device__ __align__(16) short g_lw[262144];
// packed fp16 [ef|df] rows, in SORTED edge order: M x 64
__device__ __align__(16) short g_efdf[(size_t)M * 64];
// fp16 shadow of state (edge-input view), rewritten per layer
__device__ __align__(16) short g_sbf[(size_t)N * D];
// sort machinery
__device__ int g_cnt[N];       // histogram -> exclusive offsets -> scatter cursors
__device__ int g_part[NBLK];   // scan partials
__device__ int g_ssrc[M];      // src, sorted by dst
__device__ int g_sdst[M];      // dst, sorted
__device__ int g_inv[M];       // sorted position -> original edge

__device__ __forceinline__ float sigm(float x) { return 1.0f / (1.0f + __expf(-x)); }

__device__ __forceinline__ short f2bf(float f) {
    unsigned u = __builtin_bit_cast(unsigned, f);
    u = (u + 0x7FFFu + ((u >> 16) & 1u)) >> 16;   // RNE
    return (short)u;
}
// bf16 pair pack (LSTM path)
__device__ __forceinline__ unsigned pk2(float a, float b) {
    __hip_bfloat162 h = __float22bfloat162_rn(float2{a, b});
    unsigned u;
    __builtin_memcpy(&u, &h, 4);
    return u;
}
// fp16 pair pack: v_cvt_pkrtz_f16_f32 (1 op)
__device__ __forceinline__ unsigned pkh(float a, float b) {
    auto h = __builtin_amdgcn_cvt_pkrtz(a, b);
    unsigned u;
    __builtin_memcpy(&u, &h, 4);
    return u;
}
__device__ __forceinline__ short f2h(float f) {
    _Float16 h = (_Float16)f;
    return __builtin_bit_cast(short, h);
}
__device__ __forceinline__ float h2f(short s) {
    _Float16 h = __builtin_bit_cast(_Float16, s);
    return (float)h;
}

// ---------------- sort-by-dst (counting sort, per call) ----------------
__global__ void zero_cnt_kernel() {
    for (int i = blockIdx.x * 256 + threadIdx.x; i < N; i += gridDim.x * 256) g_cnt[i] = 0;
}
__global__ void hist_kernel(const int* __restrict__ edge) {
    int e = blockIdx.x * 256 + threadIdx.x;
    if (e < M) atomicAdd(&g_cnt[edge[e * 2 + 1]], 1);
}
__global__ void scanA_kernel() {   // block sums
    __shared__ int red[256];
    const int t = threadIdx.x;
    const int idx = blockIdx.x * 256 + t;
    red[t] = (idx < N) ? g_cnt[idx] : 0;
    __syncthreads();
#pragma unroll
    for (int s = 128; s > 0; s >>= 1) {
        if (t < s) red[t] += red[t + s];
        __syncthreads();
    }
    if (t == 0) g_part[blockIdx.x] = red[0];
}
__global__ void scanB_kernel() {   // 1 block: exclusive scan of partials
    __shared__ int sh[256];
    const int t = threadIdx.x;
    int v = (t < NBLK) ? g_part[t] : 0;
    sh[t] = v;
    __syncthreads();
    int x = v;
    for (int s = 1; s < 256; s <<= 1) {
        int y = (t >= s) ? sh[t - s] : 0;
        __syncthreads();
        x += y; sh[t] = x;
        __syncthreads();
    }
    if (t < NBLK) g_part[t] = x - v;
}
__global__ void scanC_kernel() {   // per-block exclusive scan + base
    __shared__ int sh[256];
    const int t = threadIdx.x;
    const int idx = blockIdx.x * 256 + t;
    int v = (idx < N) ? g_cnt[idx] : 0;
    sh[t] = v;
    __syncthreads();
    int x = v;
    for (int s = 1; s < 256; s <<= 1) {
        int y = (t >= s) ? sh[t - s] : 0;
        __syncthreads();
        x += y; sh[t] = x;
        __syncthreads();
    }
    if (idx < N) g_cnt[idx] = g_part[blockIdx.x] + x - v;
}
__global__ void scatter_kernel(const int* __restrict__ edge) {
    int e = blockIdx.x * 256 + threadIdx.x;
    if (e < M) {
        const int s = edge[e * 2], d = edge[e * 2 + 1];
        const int p = atomicAdd(&g_cnt[d], 1);
        g_ssrc[p] = s;
        g_sdst[p] = d;
        g_inv[p]  = e;
    }
}

// ---------------- packs ----------------
__global__ void pack_edge(const float* __restrict__ w0m, const float* __restrict__ w0a,
                          const float* __restrict__ w1m, const float* __restrict__ w1a) {
    int gid = blockIdx.x * 256 + threadIdx.x;          // 0..163839
    int ii = gid / 81920;
    int r  = gid % 81920;
    int p  = r / 40960;  r %= 40960;
    int which = (r >= 24576) ? 1 : 0;
    int r2 = which ? r - 24576 : r;
    int e    = r2 & 7;
    int f    = r2 >> 3;
    int lane = f & 63;
    int ktct = f >> 6;
    int ct = ktct & 3, kt = ktct >> 2;
    int k   = kt * 16 + ((lane >> 5) << 3) + e;
    int col = ct * 32 + (lane & 31);
    const float* w0 = p ? w0a : w0m;
    const float* w1 = p ? w1a : w1m;
    float v = which ? w1[((size_t)ii * D + k) * D + col]
                    : w0[((size_t)ii * IN + k) * D + col];
    g_wp[gid] = f2h(v);
}

__global__ void pack_lstm(const float* __restrict__ wih, const float* __restrict__ whh) {
    int gid = blockIdx.x * 256 + threadIdx.x;          // 0..262143
    int ii = gid >> 17;
    int r  = gid & 131071;
    int e = r & 7, f = r >> 3;
    int lane = f & 63, rest = f >> 6;
    int cf = rest & 15, kt = rest >> 4;
    int col = cf * 32 + (lane & 31);
    int k   = (kt & 7) * 16 + ((lane >> 5) << 3) + e;
    const float* src = (kt < 8) ? wih : whh;
    g_lw[gid] = f2bf(src[((size_t)ii * 512 + col) * D + k]);
}

// ef/df -> fp16, gathered via inverse perm, written CONTIGUOUS in sorted order
__global__ void pack_efdf(const float* __restrict__ ef, const float* __restrict__ df) {
    int gid = blockIdx.x * 256 + threadIdx.x;          // 0..6399999
    int p = gid >> 3, c0 = (gid & 7) * 8;
    const int e = g_inv[p];
    const float* s = (c0 < 32) ? (ef + (size_t)e * 32 + c0) : (df + (size_t)e * 32 + (c0 - 32));
    float4 u0 = *(const float4*)s, u1 = *(const float4*)(s + 4);
    short8 t;
    unsigned* tp = (unsigned*)&t;
    tp[0] = pkh(u0.x, u0.y); tp[1] = pkh(u0.z, u0.w);
    tp[2] = pkh(u1.x, u1.y); tp[3] = pkh(u1.z, u1.w);
    *(short8*)(g_efdf + (size_t)gid * 8) = t;
}

// ---------------- init: state/state_c copy + fp16 shadow + zero msg ----------------
__global__ void init_kernel(const float4* __restrict__ nf, const float4* __restrict__ nfc,
                            float4* __restrict__ state, float4* __restrict__ state_c,
                            float4* __restrict__ msg) {
    const int total = N * D / 4;
    const float4 z = make_float4(0.f, 0.f, 0.f, 0.f);
    for (int i = blockIdx.x * blockDim.x + threadIdx.x; i < total; i += gridDim.x * blockDim.x) {
        float4 v = nf[i];
        state[i]   = v;
        state_c[i] = nfc[i];
        short4v b;
        unsigned* bp = (unsigned*)&b;
        bp[0] = pkh(v.x, v.y); bp[1] = pkh(v.z, v.w);
        *(short4v*)(g_sbf + (size_t)i * 4) = b;
        msg[i] = z;
    }
}

// ---------------- edge kernel: 16KB-chunk 2-deep prefetch fp16 pipeline, 512 threads ----------------
#define MFMA16(a, b, c) __builtin_amdgcn_mfma_f32_32x32x16_f16(a, b, c, 0, 0, 0)
#define MFMABF(a, b, c) __builtin_amdgcn_mfma_f32_32x32x16_bf16(a, b, c, 0, 0, 0)

// chunk gc: issue load(gc+2) -> MFMA(gc from LDS) -> store held load(gc+1) -> barrier
template<int BASE, int NC, bool FROM_H>
__device__ __forceinline__ void gemm_phase(const short8* __restrict__ gsrc, short8* wb,
                                           short8 gA[2], const half8 a1[12],
                                           const short (*hsr)[136],
                                           int tid, int lane, int cg, int half,
                                           f32x16& o0, f32x16& o1) {
    f32x16 acc0 = {}, acc1 = {};
#pragma unroll
    for (int c = 0; c < NC; ++c) {
        const int gc = BASE + c;
        short8 gB0, gB1;
        if (gc + 2 < NCH) {
            gB0 = gsrc[(size_t)(gc + 2) * 1024 + tid];
            gB1 = gsrc[(size_t)(gc + 2) * 1024 + tid + 512];
        }
        const short8* buf = wb + (gc & 1) * 1024;
#pragma unroll
        for (int kl = 0; kl < 4; ++kl) {
            const int kt = c * 4 + kl;
            half8 a = FROM_H
                ? __builtin_bit_cast(half8, *(const short8*)&hsr[lane & 31][kt * 16 + half])
                : a1[kt];
            half8 b0 = __builtin_bit_cast(half8, buf[(kl * 4 + cg * 2 + 0) * 64 + lane]);
            half8 b1 = __builtin_bit_cast(half8, buf[(kl * 4 + cg * 2 + 1) * 64 + lane]);
            acc0 = MFMA16(a, b0, acc0);
            acc1 = MFMA16(a, b1, acc1);
        }
        if (gc + 1 < NCH) {
            short8* d = wb + ((gc + 1) & 1) * 1024;
            d[tid] = gA[0]; d[tid + 512] = gA[1];
        }
        __syncthreads();
        if (gc + 2 < NCH) { gA[0] = gB0; gA[1] = gB1; }
    }
    o0 = acc0; o1 = acc1;
}

__device__ __forceinline__ void hwrite(short (*hsr)[136], const f32x16& a0, const f32x16& a1v,
                                       const float* __restrict__ b0, int lane, int cg) {
#pragma unroll
    for (int ct = 0; ct < 2; ++ct) {
        const int col = cg * 64 + ct * 32 + (lane & 31);
        const float bv = b0[col];
        f32x16 a = ct ? a1v : a0;
#pragma unroll
        for (int rp = 0; rp < 8; ++rp) {
            const int reg = rp * 2;
            const int row = (reg & 3) + 8 * (reg >> 2) + 4 * (lane >> 5);
            const unsigned pr = pkh(fmaxf(a[reg] + bv, 0.f), fmaxf(a[reg + 1] + bv, 0.f));
            hsr[row][col]     = (short)(pr & 0xFFFF);
            hsr[row + 1][col] = (short)(pr >> 16);
        }
    }
}

__global__ __launch_bounds__(512, 4)
void edge_mfma(int ii,
               const float* __restrict__ b0m, const float* __restrict__ b1m,
               const float* __restrict__ b0a, const float* __restrict__ b1a,
               float* __restrict__ state_msg) {
    // pool: wb 32768 | hs 4x32x136x2 = 34816 | sdst 512  = 68096 B (2 blocks/CU)
    // epilogue overlays [0, 33792) as f32 vt[64][132] (2 passes); wb+hs dead by then
    __shared__ __align__(16) char pool[68096];
    short8* wb = (short8*)pool;
    short (*hs)[32][136] = (short(*)[32][136])(pool + 32768);
    int* sdst = (int*)(pool + 67584);

    const int tid  = threadIdx.x;
    const int lane = tid & 63;
    const int w    = tid >> 6;          // 0..7
    const int rt   = w >> 1;            // 0..3  (32-edge group)
    const int cg   = w & 1;             // 0..1  (64-col group)
    const int e0   = blockIdx.x * TE;

    if (tid < TE) sdst[tid] = g_sdst[e0 + tid];

    // ---- gather A1 fragments from fp16 shadow (sorted edge order)
    const int er   = e0 + rt * 32 + (lane & 31);
    const int half = (lane >> 5) << 3;
    const int s  = g_ssrc[er];
    const int d2 = g_sdst[er];
    const short* srow = g_sbf + (size_t)s  * D;
    const short* drow = g_sbf + (size_t)d2 * D;
    half8 a1[12];
#pragma unroll
    for (int kt = 0; kt < 8; ++kt) {
        const int k0 = kt * 16 + half;
        half8 sv = __builtin_bit_cast(half8, *(const short8*)(srow + k0));
        half8 dv = __builtin_bit_cast(half8, *(const short8*)(drow + k0));
        a1[kt] = sv - dv;                      // 4x v_pk_add_f16
    }
#pragma unroll
    for (int kt = 8; kt < 12; ++kt)
        a1[kt] = __builtin_bit_cast(half8, *(const short8*)(g_efdf + (size_t)er * 64 + (kt - 8) * 16 + half));

    const short8* gsrc = (const short8*)(g_wp + (size_t)ii * 81920);

    // prologue: stage chunk 0 to LDS; hold chunk 1 in regs
    wb[tid] = gsrc[tid];
    wb[tid + 512] = gsrc[tid + 512];
    short8 gA[2];
    gA[0] = gsrc[1024 + tid];
    gA[1] = gsrc[1024 + tid + 512];
    __syncthreads();

    f32x16 t0, t1, m0, m1, c0, c1;
    gemm_phase<0, 3, false>(gsrc, wb, gA, a1, hs[rt], tid, lane, cg, half, t0, t1); // msg GEMM1
    hwrite(hs[rt], t0, t1, b0m, lane, cg);
    __syncthreads();
    gemm_phase<3, 2, true>(gsrc, wb, gA, a1, hs[rt], tid, lane, cg, half, m0, m1);  // msg GEMM2

    // pack (msg + bias) to fp16 pairs: frees 16 regs across the att path
    unsigned mb[16];
#pragma unroll
    for (int ct = 0; ct < 2; ++ct) {
        const float bm = b1m[cg * 64 + ct * 32 + (lane & 31)];
        f32x16 mv = ct ? m1 : m0;
#pragma unroll
        for (int rp = 0; rp < 8; ++rp)
            mb[ct * 8 + rp] = pkh(mv[rp * 2] + bm, mv[rp * 2 + 1] + bm);
    }

    gemm_phase<5, 3, false>(gsrc, wb, gA, a1, hs[rt], tid, lane, cg, half, t0, t1); // att GEMM1
    hwrite(hs[rt], t0, t1, b0a, lane, cg);
    __syncthreads();
    gemm_phase<8, 2, true>(gsrc, wb, gA, a1, hs[rt], tid, lane, cg, half, c0, c1);  // att GEMM2

    // ---- 2-pass combine (f32 vt overlay) + segmented reduction over sorted runs
    float (*vt)[132] = (float(*)[132])pool;
    const int colr = tid & 127;
    const int sub  = tid >> 7;          // 0..3
#pragma unroll
    for (int pass = 0; pass < 2; ++pass) {
        if ((rt >> 1) == pass) {
#pragma unroll
            for (int ct = 0; ct < 2; ++ct) {
                const int col = cg * 64 + ct * 32 + (lane & 31);
                const float ba = b1a[col];
                f32x16 av = ct ? c1 : c0;
#pragma unroll
                for (int rp = 0; rp < 8; ++rp) {
                    const int reg = rp * 2;
                    const unsigned u = mb[ct * 8 + rp];
                    const int row = (rt & 1) * 32 + (reg & 3) + 8 * (reg >> 2) + 4 * (lane >> 5);
                    vt[row][col]     = h2f((short)(u & 0xFFFF)) * sigm(av[reg] + ba);
                    vt[row + 1][col] = h2f((short)(u >> 16))    * sigm(av[reg + 1] + ba);
                }
            }
        }
        __syncthreads();
        const int gbase = pass * 64 + sub * 16;
        float run = 0.f;
        int cur = sdst[gbase];
#pragma unroll 4
        for (int r = 0; r < 16; ++r) {
            const int dd = sdst[gbase + r];
            if (dd != cur) {
                atomicAdd(state_msg + (size_t)cur * D + colr, run);
                run = 0.f; cur = dd;
            }
            run += vt[sub * 16 + r][colr];
        }
        atomicAdd(state_msg + (size_t)cur * D + colr, run);
        __syncthreads();
    }
}

// ---------------- LSTM: bf16 MFMA; non-last layer also writes relu'd state,
//                  fp16 shadow, and zeros its state_msg rows ----------------
__global__ __launch_bounds__(256, 4)
void lstm_mfma(float* __restrict__ x, float* __restrict__ hbuf, float* __restrict__ cbuf,
               int ii, int last,
               const float* __restrict__ bih, const float* __restrict__ bhh) {
    __shared__ short8 wb[2048];
    const int tid  = threadIdx.x;
    const int lane = tid & 63;
    const int w    = tid >> 6;
    const int n0   = blockIdx.x * 32;
    const int half = (lane >> 5) << 3;
    const int nl   = lane & 31;
    const int nld  = min(n0 + nl, N - 1);

    const short8* gsrc = (const short8*)(g_lw + (size_t)ii * 131072);

    {
        short8 g[4];
#pragma unroll
        for (int i = 0; i < 4; ++i) g[i] = gsrc[tid + i * 256];
#pragma unroll
        for (int i = 0; i < 4; ++i) wb[tid + i * 256] = g[i];
        __syncthreads();
    }

    f32x16 acc[4] = {};
#pragma unroll
    for (int kt = 0; kt < 16; ++kt) {
        const float* srow = (kt < 8) ? (x + (size_t)nld * D + kt * 16 + half)
                                     : (hbuf + (size_t)nld * D + (kt - 8) * 16 + half);
        float4 u0 = *(const float4*)(srow);
        float4 u1 = *(const float4*)(srow + 4);
        short8 a;
        unsigned* ap = (unsigned*)&a;
        ap[0] = pk2(u0.x, u0.y); ap[1] = pk2(u0.z, u0.w);
        ap[2] = pk2(u1.x, u1.y); ap[3] = pk2(u1.z, u1.w);

        short8 g[4];
        if (kt + 1 < 16) {
            const short8* p = gsrc + (size_t)(kt + 1) * 1024;
#pragma unroll
            for (int i = 0; i < 4; ++i) g[i] = p[tid + i * 256];
        }
        const short8* buf = wb + (kt & 1) * 1024;
#pragma unroll
        for (int q = 0; q < 4; ++q) {
            short8 b = buf[(q * 4 + w) * 64 + lane];
            acc[q] = MFMABF(a, b, acc[q]);
        }
        if (kt + 1 < 16) {
            short8* d = wb + ((kt + 1) & 1) * 1024;
#pragma unroll
            for (int i = 0; i < 4; ++i) d[tid + i * 256] = g[i];
        }
        __syncthreads();   // final iteration: all x/h reads in block are complete after this
    }

    const int col = (w << 5) + nl;
    const float bi = bih[col]       + bhh[col];
    const float bf = bih[128 + col] + bhh[128 + col];
    const float bg = bih[256 + col] + bhh[256 + col];
    const float bo = bih[384 + col] + bhh[384 + col];
#pragma unroll
    for (int reg = 0; reg < 16; ++reg) {
        const int nn = (reg & 3) + 8 * (reg >> 2) + 4 * (lane >> 5);
        const int n = n0 + nn;
        if (n < N) {
            const float gi = acc[0][reg] + bi;
            const float gf = acc[1][reg] + bf;
            const float gg = acc[2][reg] + bg;
            const float go = acc[3][reg] + bo;
            float* cp = cbuf + (size_t)n * D + col;
            const float c2 = sigm(gf) * (*cp) + sigm(gi) * tanhf(gg);
            const float h2 = sigm(go) * tanhf(c2);
            *cp = c2;
            const float ho = last ? h2 : fmaxf(h2, 0.f);
            hbuf[(size_t)n * D + col] = ho;
            if (!last) g_sbf[(size_t)n * D + col] = f2h(ho);
        }
    }

    // non-last: zero this block's state_msg rows for the next layer
    // (safe: all x reads completed before the kt-loop's final barrier)
    if (!last) {
        float4* xr = (float4*)(x + (size_t)n0 * D);
        const float4 z = make_float4(0.f, 0.f, 0.f, 0.f);
#pragma unroll
        for (int i = 0; i < 4; ++i) {
            const int idx = tid + i * 256;               // 0..1023 = 32 nodes x 32 float4
            if (n0 + (idx >> 5) < N) xr[idx] = z;
        }
    }
}

extern "C" void kernel_launch(void* const* d_in, const int* in_sizes, int n_in,
                              void* d_out, int out_size, void* d_ws, size_t ws_size,
                              hipStream_t stream) {
    const float* node_feat   = (const float*)d_in[0];
    const float* node_feat_c = (const float*)d_in[1];
    const int*   edge        = (const int*)d_in[2];
    const float* edge_feat   = (const float*)d_in[3];
    const float* dist_feat   = (const float*)d_in[4];
    const float* msg_w0 = (const float*)d_in[5];
    const float* msg_b0 = (const float*)d_in[6];
    const float* msg_w1 = (const float*)d_in[7];
    const float* msg_b1 = (const float*)d_in[8];
    const float* att_w0 = (const float*)d_in[9];
    const float* att_b0 = (const float*)d_in[10];
    const float* att_w1 = (const float*)d_in[11];
    const float* att_b1 = (const float*)d_in[12];
    const float* lstm_wih = (const float*)d_in[13];
    const float* lstm_whh = (const float*)d_in[14];
    const float* lstm_bih = (const float*)d_in[15];
    const float* lstm_bhh = (const float*)d_in[16];

    float* state     = (float*)d_out;
    float* state_c   = (float*)d_ws;
    float* state_msg = (float*)d_ws + (size_t)N * D;

    // sort edges by dst (per call; edge list static across layers)
    zero_cnt_kernel<<<256, 256, 0, stream>>>();
    hist_kernel<<<(M + 255) / 256, 256, 0, stream>>>(edge);
    scanA_kernel<<<NBLK, 256, 0, stream>>>();
    scanB_kernel<<<1, 256, 0, stream>>>();
    scanC_kernel<<<NBLK, 256, 0, stream>>>();
    scatter_kernel<<<(M + 255) / 256, 256, 0, stream>>>(edge);

    pack_efdf<<<25000, 256, 0, stream>>>(edge_feat, dist_feat);
    pack_edge<<<640, 256, 0, stream>>>(msg_w0, att_w0, msg_w1, att_w1);
    pack_lstm<<<1024, 256, 0, stream>>>(lstm_wih, lstm_whh);

    init_kernel<<<2048, 256, 0, stream>>>((const float4*)node_feat, (const float4*)node_feat_c,
                                          (float4*)state, (float4*)state_c, (float4*)state_msg);

    for (int ii = 0; ii < 2; ++ii) {
        edge_mfma<<<M / TE, 512, 0, stream>>>(
            ii,
            msg_b0 + (size_t)ii * D, msg_b1 + (size_t)ii * D,
            att_b0 + (size_t)ii * D, att_b1 + (size_t)ii * D,
            state_msg);

        lstm_mfma<<<(N + 31) / 32, 256, 0, stream>>>(
            state_msg, state, state_c, ii, (ii == 1) ? 1 : 0,
            lstm_bih + (size_t)ii * 4 * D, lstm_bhh + (size_t)ii * 4 * D);
    }
}